// Round 10
// baseline (327.866 us; speedup 1.0000x reference)
//
#include <hip/hip_runtime.h>
#include <math.h>

#define EPS 1e-5f

typedef __attribute__((address_space(3))) float lds_f;
typedef __attribute__((address_space(1))) const float glb_f;

__device__ __forceinline__ float wave_sum64(float v) {
#pragma unroll
  for (int off = 32; off >= 1; off >>= 1) v += __shfl_xor(v, off, 64);
  return v;
}

// K1: x = weather @ W_emb + b_emb + pos_encoding (4 rows/block)
__global__ __launch_bounds__(256) void k_embed(
    const float* __restrict__ weather, const float* __restrict__ coords,
    const float* __restrict__ W_emb, const float* __restrict__ b_emb,
    float* __restrict__ x) {
  int t = threadIdx.x, r = t >> 6, e = t & 63;
  int row = (blockIdx.x << 2) | r;  // b*1024 + s
  int b = row >> 10, s = row & 1023;
  __shared__ float wrow[4][32];
  if (e < 31) wrow[r][e] = weather[row * 31 + e];
  __syncthreads();
  float acc = b_emb[e];
#pragma unroll
  for (int i = 0; i < 31; ++i) acc = fmaf(wrow[r][i], W_emb[i * 64 + e], acc);
  int g = e >> 2, rem = e & 3;
  float div = __expf(-0.5756462732485115f * (float)g);
  float pe;
  if (rem == 0)      pe = sinf((float)s * div);
  else if (rem == 1) pe = cosf((float)s * div);
  else if (rem == 2) pe = sinf(coords[b * 2 + 0] * 0.017453292519943295f * div);
  else               pe = cosf(coords[b * 2 + 1] * 0.017453292519943295f * div);
  x[row * 64 + e] = acc + pe;
}

// K2: qkv projection, written straight into attention-friendly layouts:
//   q2[bh][s2][8]   (gran added)
//   kv2[bh][key][16] = K(8) || V(8)  (gran added to K)
// bh = 8*(s%8)+h ; s2 = b*128 + s/8 ; hd = e%8.  8 rows/block, thread = col.
__global__ __launch_bounds__(192) void k_qkv(
    const float* __restrict__ x, const float* __restrict__ Wq,
    const float* __restrict__ bq, const float* __restrict__ gran,
    const int* __restrict__ tidx, float* __restrict__ q2,
    float* __restrict__ kv2) {
  int t = threadIdx.x;
  int row0 = blockIdx.x << 3;
  float acc[8];
  float bias = bq[t];
#pragma unroll
  for (int r = 0; r < 8; ++r) acc[r] = bias;
  const float* xp = x + (size_t)row0 * 64;
#pragma unroll 4
  for (int k4 = 0; k4 < 16; ++k4) {
    float4 xv[8];
#pragma unroll
    for (int r = 0; r < 8; ++r) xv[r] = *(const float4*)(xp + r * 64 + k4 * 4);
    float w0 = Wq[(4 * k4 + 0) * 192 + t];
    float w1 = Wq[(4 * k4 + 1) * 192 + t];
    float w2 = Wq[(4 * k4 + 2) * 192 + t];
    float w3 = Wq[(4 * k4 + 3) * 192 + t];
#pragma unroll
    for (int r = 0; r < 8; ++r) {
      acc[r] = fmaf(xv[r].x, w0, acc[r]);
      acc[r] = fmaf(xv[r].y, w1, acc[r]);
      acc[r] = fmaf(xv[r].z, w2, acc[r]);
      acc[r] = fmaf(xv[r].w, w3, acc[r]);
    }
  }
  int cq = t & 63;
  int hh = cq >> 3, hd = t & 7;
  bool isqk = t < 128;
  int b = row0 >> 10, shi = (row0 & 1023) >> 3;
  int s2 = (b << 7) | shi;  // same for all 8 rows (row0 % 8 == 0)
#pragma unroll
  for (int r = 0; r < 8; ++r) {
    float o = acc[r];
    if (isqk) o += gran[tidx[2 * r + 1] * 64 + cq];  // (row0+r)%8 == r
    int bh = (r << 3) | hh;
    size_t base = ((size_t)(bh << 10) | s2);
    if (t < 64)       q2[(base << 3) + hd] = o;
    else if (t < 128) kv2[(base << 4) + hd] = o;
    else              kv2[(base << 4) + 8 + hd] = o;
  }
}

#define DOT8(qa, qb, ka, kb)                                            \
  fmaf((qa).x, (ka).x, fmaf((qa).y, (ka).y, fmaf((qa).z, (ka).z,        \
  fmaf((qa).w, (ka).w, fmaf((qb).x, (kb).x, fmaf((qb).y, (kb).y,        \
  fmaf((qb).z, (kb).z, (qb).w * (kb).w)))))))

// K3: flash attention. Block = (bh, 32-query chunk), 256 threads =
// 16 q-slots x 16 key-splits; lane owns queries (j0, j0+16).
// Round-9 lesson: VGPR=68 is 4 regs over the m69 occupancy cliff (waves/CU
// halve at 64) -> staging moved to global_load_lds DMA (no VGPR round-trip,
// no ds_write). Swizzle applied on the SOURCE address (rule 21: gload_lds
// writes linearly at wavebase+lane*16; XOR swizzle is an involution so
// pre-swizzled source + swizzled reads match). One barrier per tile:
// issue DMA for tile tt+1 -> buf^1, compute buf, __syncthreads() (compiler
// drains vmcnt(0) before s_barrier) -> DMA landed before buf^1 is read.
// Deferred-max softmax, one K/V row live, 4-key batches; target VGPR <= 64.
__global__ __launch_bounds__(256, 2) void k_attn(
    const float* __restrict__ q2, const float* __restrict__ kv2,
    float* __restrict__ ao) {
  int bh = blockIdx.x >> 5, chunk = blockIdx.x & 31;
  int slo = bh >> 3, h = bh & 7;
  int t = threadIdx.x;
  int qs = t >> 4, ks = t & 15;
  int j0 = (chunk << 5) | qs;      // this lane's queries: j0 and j0+16
  int o0 = ((ks >> 1) & 3) << 2;   // swizzle base (float offset)

  const float* qp0 = q2 + ((((size_t)bh << 10) | j0) << 3);
  const float* qp1 = qp0 + 128;  // query j0+16
  float4 q0a = *(const float4*)qp0, q0b = *(const float4*)(qp0 + 4);
  float4 q1a = *(const float4*)qp1, q1b = *(const float4*)(qp1 + 4);
  const float scl = 0.35355339059327373f;  // 8^-0.5 folded into q
  q0a.x *= scl; q0a.y *= scl; q0a.z *= scl; q0a.w *= scl;
  q0b.x *= scl; q0b.y *= scl; q0b.z *= scl; q0b.w *= scl;
  q1a.x *= scl; q1a.y *= scl; q1a.z *= scl; q1a.w *= scl;
  q1b.x *= scl; q1b.y *= scl; q1b.z *= scl; q1b.w *= scl;

  __shared__ float tile[2][2048];  // [buf][128 keys x 16 floats, swizzled]
  const float* kvb = kv2 + ((size_t)bh << 14);

  // source swizzle (involution): float4 i -> (i&~3) | ((i&3) ^ ((i>>3)&3))
  int sw_t = (t & ~3) | ((t & 3) ^ ((t >> 3) & 3));
  // wave-uniform LDS dest: wave w covers float4 slots [w*64, w*64+63] and
  // [256+w*64, ...]; gload_lds deposits at base + lane*16.
  int wbase = (t >> 6) << 8;  // float offset of this wave's region

  // prologue: DMA tile 0 into buf 0
  __builtin_amdgcn_global_load_lds((glb_f*)(kvb + (sw_t << 2)),
                                   (lds_f*)(&tile[0][0] + wbase), 16, 0, 0);
  __builtin_amdgcn_global_load_lds((glb_f*)(kvb + ((sw_t + 256) << 2)),
                                   (lds_f*)(&tile[0][1024] + wbase), 16, 0, 0);
  __syncthreads();

  float m0 = -1e30f, l0 = 0.f, m1 = -1e30f, l1 = 0.f;
  float a0[8], a1[8];
#pragma unroll
  for (int i = 0; i < 8; ++i) { a0[i] = 0.f; a1[i] = 0.f; }

  for (int tt = 0; tt < 8; ++tt) {
    if (tt < 7) {  // DMA next tile into the other buffer (in flight now)
      const float* srcn = kvb + ((size_t)(tt + 1) << 11);
      float* dst = &tile[(tt + 1) & 1][0];
      __builtin_amdgcn_global_load_lds((glb_f*)(srcn + (sw_t << 2)),
                                       (lds_f*)(dst + wbase), 16, 0, 0);
      __builtin_amdgcn_global_load_lds((glb_f*)(srcn + ((sw_t + 256) << 2)),
                                       (lds_f*)(dst + 1024 + wbase), 16, 0, 0);
    }
    const float* tb = tile[tt & 1];
#pragma unroll 2
    for (int b = 0; b < 2; ++b) {
      // this lane's 4 keys this batch: (b<<6)|ks, +16, +32, +48
      const float* kr = tb + (((b << 6) | ks) << 4);
      float s0, s1, s2, s3, u0, u1, u2, u3;
      {
        float4 ka = *(const float4*)(kr + o0);
        float4 kb = *(const float4*)(kr + (o0 ^ 4));
        s0 = DOT8(q0a, q0b, ka, kb); u0 = DOT8(q1a, q1b, ka, kb);
      }
      {
        float4 ka = *(const float4*)(kr + 256 + o0);
        float4 kb = *(const float4*)(kr + 256 + (o0 ^ 4));
        s1 = DOT8(q0a, q0b, ka, kb); u1 = DOT8(q1a, q1b, ka, kb);
      }
      {
        float4 ka = *(const float4*)(kr + 512 + o0);
        float4 kb = *(const float4*)(kr + 512 + (o0 ^ 4));
        s2 = DOT8(q0a, q0b, ka, kb); u2 = DOT8(q1a, q1b, ka, kb);
      }
      {
        float4 ka = *(const float4*)(kr + 768 + o0);
        float4 kb = *(const float4*)(kr + 768 + (o0 ^ 4));
        s3 = DOT8(q0a, q0b, ka, kb); u3 = DOT8(q1a, q1b, ka, kb);
      }
      float mx0 = fmaxf(fmaxf(s0, s1), fmaxf(s2, s3));
      float mx1 = fmaxf(fmaxf(u0, u1), fmaxf(u2, u3));
      if (mx0 > m0 + 8.f) {  // cold: first batch (exp(-1e30)=0) or outlier
        float esc = __expf(m0 - mx0);
        l0 *= esc;
#pragma unroll
        for (int i = 0; i < 8; ++i) a0[i] *= esc;
        m0 = mx0;
      }
      if (mx1 > m1 + 8.f) {
        float esc = __expf(m1 - mx1);
        l1 *= esc;
#pragma unroll
        for (int i = 0; i < 8; ++i) a1[i] *= esc;
        m1 = mx1;
      }
      float e0 = __expf(s0 - m0), e1 = __expf(s1 - m0);
      float e2 = __expf(s2 - m0), e3 = __expf(s3 - m0);
      float f0 = __expf(u0 - m1), f1 = __expf(u1 - m1);
      float f2 = __expf(u2 - m1), f3 = __expf(u3 - m1);
      l0 += (e0 + e1) + (e2 + e3);
      l1 += (f0 + f1) + (f2 + f3);
      {
        float4 va = *(const float4*)(kr + (o0 ^ 8));
        float4 vb = *(const float4*)(kr + (o0 ^ 12));
        a0[0] = fmaf(e0, va.x, a0[0]); a0[1] = fmaf(e0, va.y, a0[1]);
        a0[2] = fmaf(e0, va.z, a0[2]); a0[3] = fmaf(e0, va.w, a0[3]);
        a0[4] = fmaf(e0, vb.x, a0[4]); a0[5] = fmaf(e0, vb.y, a0[5]);
        a0[6] = fmaf(e0, vb.z, a0[6]); a0[7] = fmaf(e0, vb.w, a0[7]);
        a1[0] = fmaf(f0, va.x, a1[0]); a1[1] = fmaf(f0, va.y, a1[1]);
        a1[2] = fmaf(f0, va.z, a1[2]); a1[3] = fmaf(f0, va.w, a1[3]);
        a1[4] = fmaf(f0, vb.x, a1[4]); a1[5] = fmaf(f0, vb.y, a1[5]);
        a1[6] = fmaf(f0, vb.z, a1[6]); a1[7] = fmaf(f0, vb.w, a1[7]);
      }
      {
        float4 va = *(const float4*)(kr + 256 + (o0 ^ 8));
        float4 vb = *(const float4*)(kr + 256 + (o0 ^ 12));
        a0[0] = fmaf(e1, va.x, a0[0]); a0[1] = fmaf(e1, va.y, a0[1]);
        a0[2] = fmaf(e1, va.z, a0[2]); a0[3] = fmaf(e1, va.w, a0[3]);
        a0[4] = fmaf(e1, vb.x, a0[4]); a0[5] = fmaf(e1, vb.y, a0[5]);
        a0[6] = fmaf(e1, vb.z, a0[6]); a0[7] = fmaf(e1, vb.w, a0[7]);
        a1[0] = fmaf(f1, va.x, a1[0]); a1[1] = fmaf(f1, va.y, a1[1]);
        a1[2] = fmaf(f1, va.z, a1[2]); a1[3] = fmaf(f1, va.w, a1[3]);
        a1[4] = fmaf(f1, vb.x, a1[4]); a1[5] = fmaf(f1, vb.y, a1[5]);
        a1[6] = fmaf(f1, vb.z, a1[6]); a1[7] = fmaf(f1, vb.w, a1[7]);
      }
      {
        float4 va = *(const float4*)(kr + 512 + (o0 ^ 8));
        float4 vb = *(const float4*)(kr + 512 + (o0 ^ 12));
        a0[0] = fmaf(e2, va.x, a0[0]); a0[1] = fmaf(e2, va.y, a0[1]);
        a0[2] = fmaf(e2, va.z, a0[2]); a0[3] = fmaf(e2, va.w, a0[3]);
        a0[4] = fmaf(e2, vb.x, a0[4]); a0[5] = fmaf(e2, vb.y, a0[5]);
        a0[6] = fmaf(e2, vb.z, a0[6]); a0[7] = fmaf(e2, vb.w, a0[7]);
        a1[0] = fmaf(f2, va.x, a1[0]); a1[1] = fmaf(f2, va.y, a1[1]);
        a1[2] = fmaf(f2, va.z, a1[2]); a1[3] = fmaf(f2, va.w, a1[3]);
        a1[4] = fmaf(f2, vb.x, a1[4]); a1[5] = fmaf(f2, vb.y, a1[5]);
        a1[6] = fmaf(f2, vb.z, a1[6]); a1[7] = fmaf(f2, vb.w, a1[7]);
      }
      {
        float4 va = *(const float4*)(kr + 768 + (o0 ^ 8));
        float4 vb = *(const float4*)(kr + 768 + (o0 ^ 12));
        a0[0] = fmaf(e3, va.x, a0[0]); a0[1] = fmaf(e3, va.y, a0[1]);
        a0[2] = fmaf(e3, va.z, a0[2]); a0[3] = fmaf(e3, va.w, a0[3]);
        a0[4] = fmaf(e3, vb.x, a0[4]); a0[5] = fmaf(e3, vb.y, a0[5]);
        a0[6] = fmaf(e3, vb.z, a0[6]); a0[7] = fmaf(e3, vb.w, a0[7]);
        a1[0] = fmaf(f3, va.x, a1[0]); a1[1] = fmaf(f3, va.y, a1[1]);
        a1[2] = fmaf(f3, va.z, a1[2]); a1[3] = fmaf(f3, va.w, a1[3]);
        a1[4] = fmaf(f3, vb.x, a1[4]); a1[5] = fmaf(f3, vb.y, a1[5]);
        a1[6] = fmaf(f3, vb.z, a1[6]); a1[7] = fmaf(f3, vb.w, a1[7]);
      }
    }
    __syncthreads();  // drains vmcnt(0) then barrier: next buf is ready,
                      // and everyone is done reading the buf we'll overwrite
  }

  // merge the 16 key-splits (lanes 16q..16q+15) via butterfly shfl
  // (m is a reference point; partials are sum/acc of exp(s - m).)
#pragma unroll
  for (int off = 1; off <= 8; off <<= 1) {
    {
      float om = __shfl_xor(m0, off, 64);
      float ol = __shfl_xor(l0, off, 64);
      float nm = fmaxf(m0, om);
      float w1 = __expf(m0 - nm), w2 = __expf(om - nm);
      l0 = l0 * w1 + ol * w2;
#pragma unroll
      for (int i = 0; i < 8; ++i) {
        float oa = __shfl_xor(a0[i], off, 64);
        a0[i] = a0[i] * w1 + oa * w2;
      }
      m0 = nm;
    }
    {
      float om = __shfl_xor(m1, off, 64);
      float ol = __shfl_xor(l1, off, 64);
      float nm = fmaxf(m1, om);
      float w1 = __expf(m1 - nm), w2 = __expf(om - nm);
      l1 = l1 * w1 + ol * w2;
#pragma unroll
      for (int i = 0; i < 8; ++i) {
        float oa = __shfl_xor(a1[i], off, 64);
        a1[i] = a1[i] * w1 + oa * w2;
      }
      m1 = nm;
    }
  }
  // lanes 0-7 of each 16-group write query j0; lanes 8-15 write j0+16
  int jw = (ks < 8) ? j0 : (j0 + 16);
  float av = (ks < 8) ? a0[ks] * (1.0f / l0) : a1[ks - 8] * (1.0f / l1);
  int bq = jw >> 7, sq = ((jw & 127) << 3) | slo;
  ao[(((size_t)((bq << 10) | sq)) << 6) + (h << 3) + (ks & 7)] = av;
}

// K4: fused  x = LN2( x1 + relu(x1@W1+b1)@W2+b2 ),  x1 = LN1( x + ao@Wo+bo )
__global__ __launch_bounds__(256) void k_fused(
    const float* x_in, const float* __restrict__ ao,
    const float* __restrict__ Wo, const float* __restrict__ bo,
    const float* __restrict__ g1, const float* __restrict__ be1,
    const float* __restrict__ W1, const float* __restrict__ b1,
    const float* __restrict__ W2, const float* __restrict__ b2,
    const float* __restrict__ g2, const float* __restrict__ be2,
    float* x_out) {
  int t = threadIdx.x, r = t >> 6, c = t & 63;
  int row = (blockIdx.x << 2) | r;
  __shared__ float x1s[4][64];
  __shared__ float h1s[4][256];
  float acc = bo[c];
  const float* ap = ao + (size_t)row * 64;
#pragma unroll 4
  for (int k4 = 0; k4 < 16; ++k4) {
    float4 av = *(const float4*)(ap + 4 * k4);
    acc = fmaf(av.x, Wo[(4 * k4 + 0) * 64 + c], acc);
    acc = fmaf(av.y, Wo[(4 * k4 + 1) * 64 + c], acc);
    acc = fmaf(av.z, Wo[(4 * k4 + 2) * 64 + c], acc);
    acc = fmaf(av.w, Wo[(4 * k4 + 3) * 64 + c], acc);
  }
  float y = acc + x_in[(size_t)row * 64 + c];
  float s1 = wave_sum64(y), s2 = wave_sum64(y * y);
  float mean = s1 * 0.015625f, var = s2 * 0.015625f - mean * mean;
  float x1v = (y - mean) * rsqrtf(var + EPS) * g1[c] + be1[c];
  x1s[r][c] = x1v;
  __syncthreads();
  float4 acc4 = *(const float4*)(b1 + 4 * c);
#pragma unroll 4
  for (int k4 = 0; k4 < 16; ++k4) {
    float4 xv = *(const float4*)(&x1s[r][4 * k4]);
    float4 w0 = *(const float4*)(W1 + (size_t)(4 * k4 + 0) * 256 + 4 * c);
    float4 w1 = *(const float4*)(W1 + (size_t)(4 * k4 + 1) * 256 + 4 * c);
    float4 w2 = *(const float4*)(W1 + (size_t)(4 * k4 + 2) * 256 + 4 * c);
    float4 w3 = *(const float4*)(W1 + (size_t)(4 * k4 + 3) * 256 + 4 * c);
    acc4.x = fmaf(xv.x, w0.x, acc4.x); acc4.y = fmaf(xv.x, w0.y, acc4.y);
    acc4.z = fmaf(xv.x, w0.z, acc4.z); acc4.w = fmaf(xv.x, w0.w, acc4.w);
    acc4.x = fmaf(xv.y, w1.x, acc4.x); acc4.y = fmaf(xv.y, w1.y, acc4.y);
    acc4.z = fmaf(xv.y, w1.z, acc4.z); acc4.w = fmaf(xv.y, w1.w, acc4.w);
    acc4.x = fmaf(xv.z, w2.x, acc4.x); acc4.y = fmaf(xv.z, w2.y, acc4.y);
    acc4.z = fmaf(xv.z, w2.z, acc4.z); acc4.w = fmaf(xv.z, w2.w, acc4.w);
    acc4.x = fmaf(xv.w, w3.x, acc4.x); acc4.y = fmaf(xv.w, w3.y, acc4.y);
    acc4.z = fmaf(xv.w, w3.z, acc4.z); acc4.w = fmaf(xv.w, w3.w, acc4.w);
  }
  acc4.x = fmaxf(acc4.x, 0.f); acc4.y = fmaxf(acc4.y, 0.f);
  acc4.z = fmaxf(acc4.z, 0.f); acc4.w = fmaxf(acc4.w, 0.f);
  *(float4*)(&h1s[r][4 * c]) = acc4;
  __syncthreads();
  float acc2 = b2[c];
#pragma unroll 4
  for (int k4 = 0; k4 < 64; ++k4) {
    float4 hv = *(const float4*)(&h1s[r][4 * k4]);
    acc2 = fmaf(hv.x, W2[(size_t)(4 * k4 + 0) * 64 + c], acc2);
    acc2 = fmaf(hv.y, W2[(size_t)(4 * k4 + 1) * 64 + c], acc2);
    acc2 = fmaf(hv.z, W2[(size_t)(4 * k4 + 2) * 64 + c], acc2);
    acc2 = fmaf(hv.w, W2[(size_t)(4 * k4 + 3) * 64 + c], acc2);
  }
  float y2 = acc2 + x1v;
  float t1 = wave_sum64(y2), t2 = wave_sum64(y2 * y2);
  float mean2 = t1 * 0.015625f, var2 = t2 * 0.015625f - mean2 * mean2;
  x_out[(size_t)row * 64 + c] =
      (y2 - mean2) * rsqrtf(var2 + EPS) * g2[c] + be2[c];
}

// K6: out = x @ W_fc + b_fc
__global__ __launch_bounds__(256) void k_head(
    const float* __restrict__ x, const float* __restrict__ Wfc,
    const float* __restrict__ bfc, float* __restrict__ out) {
  int gid = blockIdx.x * 256 + threadIdx.x;
  int r = gid >> 5, o = gid & 31;
  if (o >= 31) return;
  float acc = bfc[o];
  const float* xr = x + (size_t)r * 64;
#pragma unroll
  for (int i = 0; i < 64; ++i) acc = fmaf(xr[i], Wfc[i * 31 + o], acc);
  out[(size_t)r * 31 + o] = acc;
}

extern "C" void kernel_launch(void* const* d_in, const int* in_sizes, int n_in,
                              void* d_out, int out_size, void* d_ws, size_t ws_size,
                              hipStream_t stream) {
  const float* weather = (const float*)d_in[0];
  const float* coords  = (const float*)d_in[1];
  const int*   tidx    = (const int*)d_in[2];
  const float* W_emb   = (const float*)d_in[3];
  const float* b_emb   = (const float*)d_in[4];
  const float* W_qkv   = (const float*)d_in[5];
  const float* b_qkv   = (const float*)d_in[6];
  const float* W_out   = (const float*)d_in[7];
  const float* b_out   = (const float*)d_in[8];
  const float* gran    = (const float*)d_in[9];
  const float* g1      = (const float*)d_in[10];
  const float* be1     = (const float*)d_in[11];
  const float* W1      = (const float*)d_in[12];
  const float* b1      = (const float*)d_in[13];
  const float* W2      = (const float*)d_in[14];
  const float* b2      = (const float*)d_in[15];
  const float* g2      = (const float*)d_in[16];
  const float* be2     = (const float*)d_in[17];
  const float* W_fc    = (const float*)d_in[18];
  const float* b_fc    = (const float*)d_in[19];
  float* out = (float*)d_out;

  // workspace (floats): x(0.5M) | q2(0.5M) | kv2(1M) | ao(0.5M) = 10 MB
  float* x   = (float*)d_ws;
  float* q2  = x + 8192 * 64;
  float* kv2 = q2 + 8192 * 64;
  float* ao  = kv2 + 8192 * 128;

  k_embed<<<2048, 256, 0, stream>>>(weather, coords, W_emb, b_emb, x);
  for (int l = 0; l < 3; ++l) {
    k_qkv<<<1024, 192, 0, stream>>>(x, W_qkv + l * 64 * 192, b_qkv + l * 192,
                                    gran + l * 31 * 64, tidx, q2, kv2);
    k_attn<<<2048, 256, 0, stream>>>(q2, kv2, ao);
    k_fused<<<2048, 256, 0, stream>>>(x, ao, W_out + l * 64 * 64, b_out + l * 64,
                                      g1 + l * 64, be1 + l * 64,
                                      W1 + l * 64 * 256, b1 + l * 256,
                                      W2 + l * 256 * 64, b2 + l * 64,
                                      g2 + l * 64, be2 + l * 64, x);
  }
  k_head<<<1024, 256, 0, stream>>>(x, W_fc, b_fc, out);
}

// Round 11
// 326.559 us; speedup vs baseline: 1.0040x; 1.0040x over previous
//
#include <hip/hip_runtime.h>
#include <math.h>

#define EPS 1e-5f

typedef __attribute__((address_space(3))) unsigned int lds_u;
typedef __attribute__((address_space(1))) const unsigned int glb_u;

__device__ __forceinline__ float wave_sum64(float v) {
#pragma unroll
  for (int off = 32; off >= 1; off >>= 1) v += __shfl_xor(v, off, 64);
  return v;
}

// bf16 helpers: one u32 = 2 bf16 (lo = elem 2i, hi = elem 2i+1)
__device__ __forceinline__ unsigned int bf16rne(float f) {
  unsigned int u = __float_as_uint(f);
  return (u + 0x7fffu + ((u >> 16) & 1u)) >> 16;
}
__device__ __forceinline__ float blo(unsigned int u) {
  return __uint_as_float(u << 16);
}
__device__ __forceinline__ float bhi(unsigned int u) {
  return __uint_as_float(u & 0xffff0000u);
}

// K1: x = weather @ W_emb + b_emb + pos_encoding (4 rows/block)
__global__ __launch_bounds__(256) void k_embed(
    const float* __restrict__ weather, const float* __restrict__ coords,
    const float* __restrict__ W_emb, const float* __restrict__ b_emb,
    float* __restrict__ x) {
  int t = threadIdx.x, r = t >> 6, e = t & 63;
  int row = (blockIdx.x << 2) | r;  // b*1024 + s
  int b = row >> 10, s = row & 1023;
  __shared__ float wrow[4][32];
  if (e < 31) wrow[r][e] = weather[row * 31 + e];
  __syncthreads();
  float acc = b_emb[e];
#pragma unroll
  for (int i = 0; i < 31; ++i) acc = fmaf(wrow[r][i], W_emb[i * 64 + e], acc);
  int g = e >> 2, rem = e & 3;
  float div = __expf(-0.5756462732485115f * (float)g);
  float pe;
  if (rem == 0)      pe = sinf((float)s * div);
  else if (rem == 1) pe = cosf((float)s * div);
  else if (rem == 2) pe = sinf(coords[b * 2 + 0] * 0.017453292519943295f * div);
  else               pe = cosf(coords[b * 2 + 1] * 0.017453292519943295f * div);
  x[row * 64 + e] = acc + pe;
}

// K2: qkv projection into attention layouts:
//   q2[bh][s2][8] fp32 (gran added)
//   kv2[bh][key][8] u32 = bf16x2: u32 0..3 = K(8 bf16), 4..7 = V(8 bf16)
// bh = 8*(s%8)+h ; s2 = b*128 + s/8 ; hd = e%8.  8 rows/block, thread = col.
__global__ __launch_bounds__(192) void k_qkv(
    const float* __restrict__ x, const float* __restrict__ Wq,
    const float* __restrict__ bq, const float* __restrict__ gran,
    const int* __restrict__ tidx, float* __restrict__ q2,
    unsigned int* __restrict__ kv2) {
  int t = threadIdx.x;
  int row0 = blockIdx.x << 3;
  float acc[8];
  float bias = bq[t];
#pragma unroll
  for (int r = 0; r < 8; ++r) acc[r] = bias;
  const float* xp = x + (size_t)row0 * 64;
#pragma unroll 4
  for (int k4 = 0; k4 < 16; ++k4) {
    float4 xv[8];
#pragma unroll
    for (int r = 0; r < 8; ++r) xv[r] = *(const float4*)(xp + r * 64 + k4 * 4);
    float w0 = Wq[(4 * k4 + 0) * 192 + t];
    float w1 = Wq[(4 * k4 + 1) * 192 + t];
    float w2 = Wq[(4 * k4 + 2) * 192 + t];
    float w3 = Wq[(4 * k4 + 3) * 192 + t];
#pragma unroll
    for (int r = 0; r < 8; ++r) {
      acc[r] = fmaf(xv[r].x, w0, acc[r]);
      acc[r] = fmaf(xv[r].y, w1, acc[r]);
      acc[r] = fmaf(xv[r].z, w2, acc[r]);
      acc[r] = fmaf(xv[r].w, w3, acc[r]);
    }
  }
  int cq = t & 63;
  int hh = cq >> 3, hd = t & 7;
  bool isqk = t < 128;
  int b = row0 >> 10, shi = (row0 & 1023) >> 3;
  int s2 = (b << 7) | shi;  // same for all 8 rows (row0 % 8 == 0)
#pragma unroll
  for (int r = 0; r < 8; ++r) {
    float o = acc[r];
    if (isqk) o += gran[tidx[2 * r + 1] * 64 + cq];  // (row0+r)%8 == r
    int bh = (r << 3) | hh;
    size_t base = ((size_t)(bh << 10) | s2);
    if (t < 64) {
      q2[(base << 3) + hd] = o;
    } else {
      // pack neighbor pairs (hd even holds lo, hd+1 holds hi); same wave.
      float nb = __shfl_down(o, 1, 64);
      if ((hd & 1) == 0) {
        unsigned int packed = bf16rne(o) | (bf16rne(nb) << 16);
        kv2[(base << 3) + (hd >> 1) + ((t < 128) ? 0 : 4)] = packed;
      }
    }
  }
}

// K3: flash attention, bf16 K/V through LDS.
// Block = (bh, 32-query chunk), 256 threads = 16 q-slots x 16 key-splits;
// lane owns queries (j0, j0+16) and keys ks+16i (one live at a time).
// Round-10 lesson: fp32 K/V was LDS-issue bound (32 ds_read_b128/lane/tile
// ~= 41us floor). bf16 K/V: one key = 32B = K slot + V slot (16B each) ->
// 2 ds_read_b128/key, unpack via shl/and.
// Slot layout (bank plan): key k's K at float4-slot (k<<1)|p, V at ^1,
// p=(k>>2)&1 -> both K-set and V-set read 2-way (free, m136). Swizzle
// applied on the DMA SOURCE address (involution, rule 21); LDS dest linear.
// Tile = 4KB (128 keys), double-buffered 8KB; one gload_lds/thread/tile.
// Deferred-max softmax per key (cold path), (256,2) cap, target VGPR<=64.
__global__ __launch_bounds__(256, 2) void k_attn(
    const float* __restrict__ q2, const unsigned int* __restrict__ kv2,
    float* __restrict__ ao) {
  int bh = blockIdx.x >> 5, chunk = blockIdx.x & 31;
  int slo = bh >> 3, h = bh & 7;
  int t = threadIdx.x;
  int qs = t >> 4, ks = t & 15;
  int j0 = (chunk << 5) | qs;  // this lane's queries: j0 and j0+16

  const float* qp0 = q2 + ((((size_t)bh << 10) | j0) << 3);
  const float* qp1 = qp0 + 128;  // query j0+16
  float4 q0a = *(const float4*)qp0, q0b = *(const float4*)(qp0 + 4);
  float4 q1a = *(const float4*)qp1, q1b = *(const float4*)(qp1 + 4);
  const float scl = 0.35355339059327373f;  // 8^-0.5 folded into q
  q0a.x *= scl; q0a.y *= scl; q0a.z *= scl; q0a.w *= scl;
  q0b.x *= scl; q0b.y *= scl; q0b.z *= scl; q0b.w *= scl;
  q1a.x *= scl; q1a.y *= scl; q1a.z *= scl; q1a.w *= scl;
  q1b.x *= scl; q1b.y *= scl; q1b.z *= scl; q1b.w *= scl;

  __shared__ unsigned int tile[2][1024];  // [buf][256 f4-slots], 8KB total
  const unsigned int* kvb = kv2 + ((size_t)bh << 13);  // 1024 keys * 8 u32

  // source float4-slot for dest slot t (involution):
  // dest slot i holds K of key i>>1 iff (i&1)==((i>>3)&1), else V.
  int src4 = (t & ~1) | ((t & 1) ^ ((t >> 3) & 1));
  // wave-uniform LDS dest: wave w covers slots [w*64, w*64+64)
  int wbase = (t >> 6) << 8;  // u32 offset of this wave's region

  // prologue: DMA tile 0 into buf 0
  __builtin_amdgcn_global_load_lds((glb_u*)(kvb + (src4 << 2)),
                                   (lds_u*)(&tile[0][0] + wbase), 16, 0, 0);
  __syncthreads();

  float m0 = -1e30f, l0 = 0.f, m1 = -1e30f, l1 = 0.f;
  float a0[8], a1[8];
#pragma unroll
  for (int i = 0; i < 8; ++i) { a0[i] = 0.f; a1[i] = 0.f; }

  int p0s = (ks >> 2) & 1;         // p(k) is i-invariant: k = ks + 16i
  int kslot0 = (ks << 1) | p0s;    // key ks slot; key ks+16i adds 32i

  for (int tt = 0; tt < 8; ++tt) {
    if (tt < 7) {  // DMA next tile into the other buffer (in flight now)
      const unsigned int* srcn = kvb + ((tt + 1) << 10);
      __builtin_amdgcn_global_load_lds(
          (glb_u*)(srcn + (src4 << 2)),
          (lds_u*)(&tile[(tt + 1) & 1][0] + wbase), 16, 0, 0);
    }
    const unsigned int* tb = tile[tt & 1];
#pragma unroll 2
    for (int i = 0; i < 8; ++i) {
      int kslot = kslot0 + (i << 5);
      uint4 kr = *(const uint4*)(tb + (kslot << 2));
      float s0, u0;
      {
        float k0 = blo(kr.x), k1 = bhi(kr.x), k2 = blo(kr.y), k3 = bhi(kr.y);
        float k4 = blo(kr.z), k5 = bhi(kr.z), k6 = blo(kr.w), k7 = bhi(kr.w);
        s0 = fmaf(q0a.x, k0, fmaf(q0a.y, k1, fmaf(q0a.z, k2, fmaf(q0a.w, k3,
             fmaf(q0b.x, k4, fmaf(q0b.y, k5, fmaf(q0b.z, k6, q0b.w * k7)))))));
        u0 = fmaf(q1a.x, k0, fmaf(q1a.y, k1, fmaf(q1a.z, k2, fmaf(q1a.w, k3,
             fmaf(q1b.x, k4, fmaf(q1b.y, k5, fmaf(q1b.z, k6, q1b.w * k7)))))));
      }
      if (s0 > m0 + 8.f) {  // cold: first key (exp(-1e30)=0) or outlier
        float esc = __expf(m0 - s0);
        l0 *= esc;
#pragma unroll
        for (int z = 0; z < 8; ++z) a0[z] *= esc;
        m0 = s0;
      }
      if (u0 > m1 + 8.f) {
        float esc = __expf(m1 - u0);
        l1 *= esc;
#pragma unroll
        for (int z = 0; z < 8; ++z) a1[z] *= esc;
        m1 = u0;
      }
      float e = __expf(s0 - m0), f = __expf(u0 - m1);
      l0 += e; l1 += f;
      uint4 vr = *(const uint4*)(tb + ((kslot ^ 1) << 2));
      {
        float v0 = blo(vr.x), v1 = bhi(vr.x), v2 = blo(vr.y), v3 = bhi(vr.y);
        float v4 = blo(vr.z), v5 = bhi(vr.z), v6 = blo(vr.w), v7 = bhi(vr.w);
        a0[0] = fmaf(e, v0, a0[0]); a0[1] = fmaf(e, v1, a0[1]);
        a0[2] = fmaf(e, v2, a0[2]); a0[3] = fmaf(e, v3, a0[3]);
        a0[4] = fmaf(e, v4, a0[4]); a0[5] = fmaf(e, v5, a0[5]);
        a0[6] = fmaf(e, v6, a0[6]); a0[7] = fmaf(e, v7, a0[7]);
        a1[0] = fmaf(f, v0, a1[0]); a1[1] = fmaf(f, v1, a1[1]);
        a1[2] = fmaf(f, v2, a1[2]); a1[3] = fmaf(f, v3, a1[3]);
        a1[4] = fmaf(f, v4, a1[4]); a1[5] = fmaf(f, v5, a1[5]);
        a1[6] = fmaf(f, v6, a1[6]); a1[7] = fmaf(f, v7, a1[7]);
      }
    }
    __syncthreads();  // drains vmcnt(0) then barrier: next buf ready, and
                      // everyone done reading the buf the next DMA overwrites
  }

  // merge the 16 key-splits (lanes 16q..16q+15) via butterfly shfl
  // (m is a reference point; partials are sum/acc of exp(s - m).)
#pragma unroll
  for (int off = 1; off <= 8; off <<= 1) {
    {
      float om = __shfl_xor(m0, off, 64);
      float ol = __shfl_xor(l0, off, 64);
      float nm = fmaxf(m0, om);
      float w1 = __expf(m0 - nm), w2 = __expf(om - nm);
      l0 = l0 * w1 + ol * w2;
#pragma unroll
      for (int i = 0; i < 8; ++i) {
        float oa = __shfl_xor(a0[i], off, 64);
        a0[i] = a0[i] * w1 + oa * w2;
      }
      m0 = nm;
    }
    {
      float om = __shfl_xor(m1, off, 64);
      float ol = __shfl_xor(l1, off, 64);
      float nm = fmaxf(m1, om);
      float w1 = __expf(m1 - nm), w2 = __expf(om - nm);
      l1 = l1 * w1 + ol * w2;
#pragma unroll
      for (int i = 0; i < 8; ++i) {
        float oa = __shfl_xor(a1[i], off, 64);
        a1[i] = a1[i] * w1 + oa * w2;
      }
      m1 = nm;
    }
  }
  // lanes 0-7 of each 16-group write query j0; lanes 8-15 write j0+16
  int jw = (ks < 8) ? j0 : (j0 + 16);
  float av = (ks < 8) ? a0[ks] * (1.0f / l0) : a1[ks - 8] * (1.0f / l1);
  int bq = jw >> 7, sq = ((jw & 127) << 3) | slo;
  ao[(((size_t)((bq << 10) | sq)) << 6) + (h << 3) + (ks & 7)] = av;
}

// K4: fused  x = LN2( x1 + relu(x1@W1+b1)@W2+b2 ),  x1 = LN1( x + ao@Wo+bo )
__global__ __launch_bounds__(256) void k_fused(
    const float* x_in, const float* __restrict__ ao,
    const float* __restrict__ Wo, const float* __restrict__ bo,
    const float* __restrict__ g1, const float* __restrict__ be1,
    const float* __restrict__ W1, const float* __restrict__ b1,
    const float* __restrict__ W2, const float* __restrict__ b2,
    const float* __restrict__ g2, const float* __restrict__ be2,
    float* x_out) {
  int t = threadIdx.x, r = t >> 6, c = t & 63;
  int row = (blockIdx.x << 2) | r;
  __shared__ float x1s[4][64];
  __shared__ float h1s[4][256];
  float acc = bo[c];
  const float* ap = ao + (size_t)row * 64;
#pragma unroll 4
  for (int k4 = 0; k4 < 16; ++k4) {
    float4 av = *(const float4*)(ap + 4 * k4);
    acc = fmaf(av.x, Wo[(4 * k4 + 0) * 64 + c], acc);
    acc = fmaf(av.y, Wo[(4 * k4 + 1) * 64 + c], acc);
    acc = fmaf(av.z, Wo[(4 * k4 + 2) * 64 + c], acc);
    acc = fmaf(av.w, Wo[(4 * k4 + 3) * 64 + c], acc);
  }
  float y = acc + x_in[(size_t)row * 64 + c];
  float s1 = wave_sum64(y), s2 = wave_sum64(y * y);
  float mean = s1 * 0.015625f, var = s2 * 0.015625f - mean * mean;
  float x1v = (y - mean) * rsqrtf(var + EPS) * g1[c] + be1[c];
  x1s[r][c] = x1v;
  __syncthreads();
  float4 acc4 = *(const float4*)(b1 + 4 * c);
#pragma unroll 4
  for (int k4 = 0; k4 < 16; ++k4) {
    float4 xv = *(const float4*)(&x1s[r][4 * k4]);
    float4 w0 = *(const float4*)(W1 + (size_t)(4 * k4 + 0) * 256 + 4 * c);
    float4 w1 = *(const float4*)(W1 + (size_t)(4 * k4 + 1) * 256 + 4 * c);
    float4 w2 = *(const float4*)(W1 + (size_t)(4 * k4 + 2) * 256 + 4 * c);
    float4 w3 = *(const float4*)(W1 + (size_t)(4 * k4 + 3) * 256 + 4 * c);
    acc4.x = fmaf(xv.x, w0.x, acc4.x); acc4.y = fmaf(xv.x, w0.y, acc4.y);
    acc4.z = fmaf(xv.x, w0.z, acc4.z); acc4.w = fmaf(xv.x, w0.w, acc4.w);
    acc4.x = fmaf(xv.y, w1.x, acc4.x); acc4.y = fmaf(xv.y, w1.y, acc4.y);
    acc4.z = fmaf(xv.y, w1.z, acc4.z); acc4.w = fmaf(xv.y, w1.w, acc4.w);
    acc4.x = fmaf(xv.z, w2.x, acc4.x); acc4.y = fmaf(xv.z, w2.y, acc4.y);
    acc4.z = fmaf(xv.z, w2.z, acc4.z); acc4.w = fmaf(xv.z, w2.w, acc4.w);
    acc4.x = fmaf(xv.w, w3.x, acc4.x); acc4.y = fmaf(xv.w, w3.y, acc4.y);
    acc4.z = fmaf(xv.w, w3.z, acc4.z); acc4.w = fmaf(xv.w, w3.w, acc4.w);
  }
  acc4.x = fmaxf(acc4.x, 0.f); acc4.y = fmaxf(acc4.y, 0.f);
  acc4.z = fmaxf(acc4.z, 0.f); acc4.w = fmaxf(acc4.w, 0.f);
  *(float4*)(&h1s[r][4 * c]) = acc4;
  __syncthreads();
  float acc2 = b2[c];
#pragma unroll 4
  for (int k4 = 0; k4 < 64; ++k4) {
    float4 hv = *(const float4*)(&h1s[r][4 * k4]);
    acc2 = fmaf(hv.x, W2[(size_t)(4 * k4 + 0) * 64 + c], acc2);
    acc2 = fmaf(hv.y, W2[(size_t)(4 * k4 + 1) * 64 + c], acc2);
    acc2 = fmaf(hv.z, W2[(size_t)(4 * k4 + 2) * 64 + c], acc2);
    acc2 = fmaf(hv.w, W2[(size_t)(4 * k4 + 3) * 64 + c], acc2);
  }
  float y2 = acc2 + x1v;
  float t1 = wave_sum64(y2), t2 = wave_sum64(y2 * y2);
  float mean2 = t1 * 0.015625f, var2 = t2 * 0.015625f - mean2 * mean2;
  x_out[(size_t)row * 64 + c] =
      (y2 - mean2) * rsqrtf(var2 + EPS) * g2[c] + be2[c];
}

// K6: out = x @ W_fc + b_fc
__global__ __launch_bounds__(256) void k_head(
    const float* __restrict__ x, const float* __restrict__ Wfc,
    const float* __restrict__ bfc, float* __restrict__ out) {
  int gid = blockIdx.x * 256 + threadIdx.x;
  int r = gid >> 5, o = gid & 31;
  if (o >= 31) return;
  float acc = bfc[o];
  const float* xr = x + (size_t)r * 64;
#pragma unroll
  for (int i = 0; i < 64; ++i) acc = fmaf(xr[i], Wfc[i * 31 + o], acc);
  out[(size_t)r * 31 + o] = acc;
}

extern "C" void kernel_launch(void* const* d_in, const int* in_sizes, int n_in,
                              void* d_out, int out_size, void* d_ws, size_t ws_size,
                              hipStream_t stream) {
  const float* weather = (const float*)d_in[0];
  const float* coords  = (const float*)d_in[1];
  const int*   tidx    = (const int*)d_in[2];
  const float* W_emb   = (const float*)d_in[3];
  const float* b_emb   = (const float*)d_in[4];
  const float* W_qkv   = (const float*)d_in[5];
  const float* b_qkv   = (const float*)d_in[6];
  const float* W_out   = (const float*)d_in[7];
  const float* b_out   = (const float*)d_in[8];
  const float* gran    = (const float*)d_in[9];
  const float* g1      = (const float*)d_in[10];
  const float* be1     = (const float*)d_in[11];
  const float* W1      = (const float*)d_in[12];
  const float* b1      = (const float*)d_in[13];
  const float* W2      = (const float*)d_in[14];
  const float* b2      = (const float*)d_in[15];
  const float* g2      = (const float*)d_in[16];
  const float* be2     = (const float*)d_in[17];
  const float* W_fc    = (const float*)d_in[18];
  const float* b_fc    = (const float*)d_in[19];
  float* out = (float*)d_out;

  // workspace (floats): x(0.5M) | q2(0.5M) | kv2(0.5M u32) | ao(0.5M) = 8 MB
  float* x   = (float*)d_ws;
  float* q2  = x + 8192 * 64;
  unsigned int* kv2 = (unsigned int*)(q2 + 8192 * 64);
  float* ao  = (float*)(kv2 + 8192 * 64);

  k_embed<<<2048, 256, 0, stream>>>(weather, coords, W_emb, b_emb, x);
  for (int l = 0; l < 3; ++l) {
    k_qkv<<<1024, 192, 0, stream>>>(x, W_qkv + l * 64 * 192, b_qkv + l * 192,
                                    gran + l * 31 * 64, tidx, q2, kv2);
    k_attn<<<2048, 256, 0, stream>>>(q2, kv2, ao);
    k_fused<<<2048, 256, 0, stream>>>(x, ao, W_out + l * 64 * 64, b_out + l * 64,
                                      g1 + l * 64, be1 + l * 64,
                                      W1 + l * 64 * 256, b1 + l * 256,
                                      W2 + l * 256 * 64, b2 + l * 64,
                                      g2 + l * 64, be2 + l * 64, x);
  }
  k_head<<<1024, 256, 0, stream>>>(x, W_fc, b_fc, out);
}

// Round 12
// 266.710 us; speedup vs baseline: 1.2293x; 1.2244x over previous
//
#include <hip/hip_runtime.h>
#include <math.h>

#define EPS 1e-5f

typedef float f32x16 __attribute__((ext_vector_type(16)));
typedef short short8 __attribute__((ext_vector_type(8)));

union U4S8 { uint4 u; short8 s; };

__device__ __forceinline__ float wave_sum64(float v) {
#pragma unroll
  for (int off = 32; off >= 1; off >>= 1) v += __shfl_xor(v, off, 64);
  return v;
}

__device__ __forceinline__ unsigned int bf16rne(float f) {
  unsigned int u = __float_as_uint(f);
  return (u + 0x7fffu + ((u >> 16) & 1u)) >> 16;
}
__device__ __forceinline__ unsigned int cvt_pk_bf16(float lo, float hi) {
  unsigned int r;
  asm("v_cvt_pk_bf16_f32 %0, %1, %2" : "=v"(r) : "v"(lo), "v"(hi));
  return r;
}

// K1: x = weather @ W_emb + b_emb + pos_encoding (4 rows/block)
__global__ __launch_bounds__(256) void k_embed(
    const float* __restrict__ weather, const float* __restrict__ coords,
    const float* __restrict__ W_emb, const float* __restrict__ b_emb,
    float* __restrict__ x) {
  int t = threadIdx.x, r = t >> 6, e = t & 63;
  int row = (blockIdx.x << 2) | r;  // b*1024 + s
  int b = row >> 10, s = row & 1023;
  __shared__ float wrow[4][32];
  if (e < 31) wrow[r][e] = weather[row * 31 + e];
  __syncthreads();
  float acc = b_emb[e];
#pragma unroll
  for (int i = 0; i < 31; ++i) acc = fmaf(wrow[r][i], W_emb[i * 64 + e], acc);
  int g = e >> 2, rem = e & 3;
  float div = __expf(-0.5756462732485115f * (float)g);
  float pe;
  if (rem == 0)      pe = sinf((float)s * div);
  else if (rem == 1) pe = cosf((float)s * div);
  else if (rem == 2) pe = sinf(coords[b * 2 + 0] * 0.017453292519943295f * div);
  else               pe = cosf(coords[b * 2 + 1] * 0.017453292519943295f * div);
  x[row * 64 + e] = acc + pe;
}

// K2: qkv projection into MFMA-attention layouts (all bf16):
//   qb[bh][s2][8 bf16]  = (q + gran) * 8^-0.5
//   kb[bh][s2][8 bf16]  = (k + gran)
//   vt[bh][d][1024 key] = v transposed
// bh = 8*(s%8)+h ; s2 = b*128 + s/8 ; hd = e%8.  8 rows/block, thread = col.
__global__ __launch_bounds__(192) void k_qkv(
    const float* __restrict__ x, const float* __restrict__ Wq,
    const float* __restrict__ bq, const float* __restrict__ gran,
    const int* __restrict__ tidx, unsigned int* __restrict__ qb,
    unsigned int* __restrict__ kbuf, unsigned short* __restrict__ vt) {
  int t = threadIdx.x;
  int row0 = blockIdx.x << 3;
  float acc[8];
  float bias = bq[t];
#pragma unroll
  for (int r = 0; r < 8; ++r) acc[r] = bias;
  const float* xp = x + (size_t)row0 * 64;
#pragma unroll 4
  for (int k4 = 0; k4 < 16; ++k4) {
    float4 xv[8];
#pragma unroll
    for (int r = 0; r < 8; ++r) xv[r] = *(const float4*)(xp + r * 64 + k4 * 4);
    float w0 = Wq[(4 * k4 + 0) * 192 + t];
    float w1 = Wq[(4 * k4 + 1) * 192 + t];
    float w2 = Wq[(4 * k4 + 2) * 192 + t];
    float w3 = Wq[(4 * k4 + 3) * 192 + t];
#pragma unroll
    for (int r = 0; r < 8; ++r) {
      acc[r] = fmaf(xv[r].x, w0, acc[r]);
      acc[r] = fmaf(xv[r].y, w1, acc[r]);
      acc[r] = fmaf(xv[r].z, w2, acc[r]);
      acc[r] = fmaf(xv[r].w, w3, acc[r]);
    }
  }
  int cq = t & 63;
  int hh = cq >> 3, hd = t & 7;
  int b = row0 >> 10, shi = (row0 & 1023) >> 3;
  int s2 = (b << 7) | shi;  // same for all 8 rows (row0 % 8 == 0)
  const float scl = 0.35355339059327373f;  // 8^-0.5 folded into q
#pragma unroll
  for (int r = 0; r < 8; ++r) {
    float o = acc[r];
    if (t < 128) o += gran[tidx[2 * r + 1] * 64 + cq];  // (row0+r)%8 == r
    int bh = (r << 3) | hh;
    if (t < 64) {
      o *= scl;
      float nb = __shfl_down(o, 1, 64);
      if ((hd & 1) == 0)
        qb[((((size_t)bh << 10) | s2) << 2) + (hd >> 1)] =
            bf16rne(o) | (bf16rne(nb) << 16);
    } else if (t < 128) {
      float nb = __shfl_down(o, 1, 64);
      if ((hd & 1) == 0)
        kbuf[((((size_t)bh << 10) | s2) << 2) + (hd >> 1)] =
            bf16rne(o) | (bf16rne(nb) << 16);
    } else {
      vt[((size_t)bh << 13) + (hd << 10) + s2] = (unsigned short)bf16rne(o);
    }
  }
}

// K3: MFMA flash attention (mfma_f32_32x32x16_bf16), no LDS.
// Verified C/D layout (m74/m101): col=lane&31, row=(reg&3)+8*(reg>>2)+4*(lane>>5).
// A: row=lane&31, k=(lane>>5)*8+j.  B: col=lane&31, k=(lane>>5)*8+j.
// Swapped QK^T: S = mfma(A=K[32key,16k(8 used)], B=Q^T) -> lane holds 16
// scores of query (lane&31); keys {0-3,8-11,16-19,24-27}+4*(lane>>5).
// Softmax: lane-local + shfl_xor(32) shared max (pair shares a query).
// PV: O^T = mfma(A=V^T[32d(8 used),16key], B=P^T); P packed bf16 via
// v_cvt_pk_bf16_f32, redistributed by 8 shfl_xor(32)+cndmask; 2 PV per 32 keys.
// K(16KB/bh) + V^T(16KB/bh) are L1/L2 resident; reads fully coalesced; no
// barriers. Wave = 32 queries x all 1024 keys; block = 4 waves; grid 64*8.
__global__ __launch_bounds__(256, 2) void k_attn(
    const unsigned int* __restrict__ qb, const unsigned int* __restrict__ kbuf,
    const unsigned short* __restrict__ vt, float* __restrict__ ao) {
  int bh = blockIdx.x >> 3, chunk = blockIdx.x & 7;
  int slo = bh >> 3, h = bh & 7;
  int t = threadIdx.x;
  int l = t & 63, w = t >> 6;
  int lq = l & 31, g = l >> 5;
  bool kl = (l < 32);     // real lanes for A(K) / B(Q) fragments
  bool vl = (lq < 8);     // real lanes for A(V^T) fragment (d = lq)
  int q = (chunk << 7) + (w << 5) + lq;  // this lane's query (s2 index)

  U4S8 qf;
  qf.u = make_uint4(0, 0, 0, 0);
  if (kl) qf.u = *(const uint4*)(qb + ((((size_t)bh << 10) + q) << 2));

  const uint4* kp = (const uint4*)(kbuf + ((size_t)bh << 12));
  const unsigned short* vp = vt + ((size_t)bh << 13);

  f32x16 O, Z;
#pragma unroll
  for (int i = 0; i < 16; ++i) { O[i] = 0.f; Z[i] = 0.f; }
  float m = -1e30f, ls = 0.f;

  for (int kblk = 0; kblk < 32; ++kblk) {  // 32 keys per iteration
    U4S8 af;
    af.u = make_uint4(0, 0, 0, 0);
    if (kl) af.u = kp[(kblk << 5) + lq];
    f32x16 S = __builtin_amdgcn_mfma_f32_32x32x16_bf16(af.s, qf.s, Z, 0, 0, 0);

    float mx = S[0];
#pragma unroll
    for (int i = 1; i < 16; ++i) mx = fmaxf(mx, S[i]);
    mx = fmaxf(mx, __shfl_xor(mx, 32, 64));  // shared max across lane pair
    if (mx > m + 8.f) {  // deferred-max cold path (always on first block)
      float esc = __expf(m - mx);
      ls *= esc;
      O *= esc;
      m = mx;
    }
    float p[16];
#pragma unroll
    for (int i = 0; i < 16; ++i) p[i] = __expf(S[i] - m);
    float s01 = (p[0] + p[1]) + (p[2] + p[3]);
    float s23 = (p[4] + p[5]) + (p[6] + p[7]);
    float s45 = (p[8] + p[9]) + (p[10] + p[11]);
    float s67 = (p[12] + p[13]) + (p[14] + p[15]);
    ls += (s01 + s23) + (s45 + s67);

    // pack P to bf16 pairs; key order per D-row map
    unsigned va = cvt_pk_bf16(p[0], p[1]),  vb = cvt_pk_bf16(p[2], p[3]);
    unsigned vc = cvt_pk_bf16(p[4], p[5]),  vd = cvt_pk_bf16(p[6], p[7]);
    unsigned ve = cvt_pk_bf16(p[8], p[9]),  vf = cvt_pk_bf16(p[10], p[11]);
    unsigned vg = cvt_pk_bf16(p[12], p[13]), vh = cvt_pk_bf16(p[14], p[15]);
    unsigned sa = __shfl_xor((int)va, 32, 64), sb = __shfl_xor((int)vb, 32, 64);
    unsigned sc = __shfl_xor((int)vc, 32, 64), sd = __shfl_xor((int)vd, 32, 64);
    unsigned se = __shfl_xor((int)ve, 32, 64), sf = __shfl_xor((int)vf, 32, 64);
    unsigned sg = __shfl_xor((int)vg, 32, 64), sh = __shfl_xor((int)vh, 32, 64);
    // B2 fragments (P^T): k-rows (lane>>5)*8+j
    U4S8 b1, b2;
    b1.u.x = kl ? va : sc;  b1.u.y = kl ? vb : sd;   // PV1: keys 0-15
    b1.u.z = kl ? sa : vc;  b1.u.w = kl ? sb : vd;
    b2.u.x = kl ? ve : sg;  b2.u.y = kl ? vf : sh;   // PV2: keys 16-31
    b2.u.z = kl ? se : vg;  b2.u.w = kl ? sf : vh;

    U4S8 v1, v2;
    v1.u = make_uint4(0, 0, 0, 0);
    v2.u = make_uint4(0, 0, 0, 0);
    if (vl) {  // A2 = V^T: row d=lq, keys kblk*32 + g*8 + j  (and +16)
      const unsigned short* vb8 = vp + (lq << 10) + (kblk << 5) + (g << 3);
      v1.u = *(const uint4*)vb8;
      v2.u = *(const uint4*)(vb8 + 16);
    }
    O = __builtin_amdgcn_mfma_f32_32x32x16_bf16(v1.s, b1.s, O, 0, 0, 0);
    O = __builtin_amdgcn_mfma_f32_32x32x16_bf16(v2.s, b2.s, O, 0, 0, 0);
  }

  ls += __shfl_xor(ls, 32, 64);  // pair partials share m -> plain add
  float inv = 1.0f / ls;
  // O regs 0-3 = O[d = 4g+reg][q]; write natural [b,s,e] layout
  int bq = q >> 7, sq = ((q & 127) << 3) | slo;
  float* op = ao + (((size_t)((bq << 10) | sq)) << 6) + (h << 3) + (g << 2);
  *(float4*)op = make_float4(O[0] * inv, O[1] * inv, O[2] * inv, O[3] * inv);
}

// K4: fused  x = LN2( x1 + relu(x1@W1+b1)@W2+b2 ),  x1 = LN1( x + ao@Wo+bo )
__global__ __launch_bounds__(256) void k_fused(
    const float* x_in, const float* __restrict__ ao,
    const float* __restrict__ Wo, const float* __restrict__ bo,
    const float* __restrict__ g1, const float* __restrict__ be1,
    const float* __restrict__ W1, const float* __restrict__ b1,
    const float* __restrict__ W2, const float* __restrict__ b2,
    const float* __restrict__ g2, const float* __restrict__ be2,
    float* x_out) {
  int t = threadIdx.x, r = t >> 6, c = t & 63;
  int row = (blockIdx.x << 2) | r;
  __shared__ float x1s[4][64];
  __shared__ float h1s[4][256];
  float acc = bo[c];
  const float* ap = ao + (size_t)row * 64;
#pragma unroll 4
  for (int k4 = 0; k4 < 16; ++k4) {
    float4 av = *(const float4*)(ap + 4 * k4);
    acc = fmaf(av.x, Wo[(4 * k4 + 0) * 64 + c], acc);
    acc = fmaf(av.y, Wo[(4 * k4 + 1) * 64 + c], acc);
    acc = fmaf(av.z, Wo[(4 * k4 + 2) * 64 + c], acc);
    acc = fmaf(av.w, Wo[(4 * k4 + 3) * 64 + c], acc);
  }
  float y = acc + x_in[(size_t)row * 64 + c];
  float s1 = wave_sum64(y), s2 = wave_sum64(y * y);
  float mean = s1 * 0.015625f, var = s2 * 0.015625f - mean * mean;
  float x1v = (y - mean) * rsqrtf(var + EPS) * g1[c] + be1[c];
  x1s[r][c] = x1v;
  __syncthreads();
  float4 acc4 = *(const float4*)(b1 + 4 * c);
#pragma unroll 4
  for (int k4 = 0; k4 < 16; ++k4) {
    float4 xv = *(const float4*)(&x1s[r][4 * k4]);
    float4 w0 = *(const float4*)(W1 + (size_t)(4 * k4 + 0) * 256 + 4 * c);
    float4 w1 = *(const float4*)(W1 + (size_t)(4 * k4 + 1) * 256 + 4 * c);
    float4 w2 = *(const float4*)(W1 + (size_t)(4 * k4 + 2) * 256 + 4 * c);
    float4 w3 = *(const float4*)(W1 + (size_t)(4 * k4 + 3) * 256 + 4 * c);
    acc4.x = fmaf(xv.x, w0.x, acc4.x); acc4.y = fmaf(xv.x, w0.y, acc4.y);
    acc4.z = fmaf(xv.x, w0.z, acc4.z); acc4.w = fmaf(xv.x, w0.w, acc4.w);
    acc4.x = fmaf(xv.y, w1.x, acc4.x); acc4.y = fmaf(xv.y, w1.y, acc4.y);
    acc4.z = fmaf(xv.y, w1.z, acc4.z); acc4.w = fmaf(xv.y, w1.w, acc4.w);
    acc4.x = fmaf(xv.z, w2.x, acc4.x); acc4.y = fmaf(xv.z, w2.y, acc4.y);
    acc4.z = fmaf(xv.z, w2.z, acc4.z); acc4.w = fmaf(xv.z, w2.w, acc4.w);
    acc4.x = fmaf(xv.w, w3.x, acc4.x); acc4.y = fmaf(xv.w, w3.y, acc4.y);
    acc4.z = fmaf(xv.w, w3.z, acc4.z); acc4.w = fmaf(xv.w, w3.w, acc4.w);
  }
  acc4.x = fmaxf(acc4.x, 0.f); acc4.y = fmaxf(acc4.y, 0.f);
  acc4.z = fmaxf(acc4.z, 0.f); acc4.w = fmaxf(acc4.w, 0.f);
  *(float4*)(&h1s[r][4 * c]) = acc4;
  __syncthreads();
  float acc2 = b2[c];
#pragma unroll 4
  for (int k4 = 0; k4 < 64; ++k4) {
    float4 hv = *(const float4*)(&h1s[r][4 * k4]);
    acc2 = fmaf(hv.x, W2[(size_t)(4 * k4 + 0) * 64 + c], acc2);
    acc2 = fmaf(hv.y, W2[(size_t)(4 * k4 + 1) * 64 + c], acc2);
    acc2 = fmaf(hv.z, W2[(size_t)(4 * k4 + 2) * 64 + c], acc2);
    acc2 = fmaf(hv.w, W2[(size_t)(4 * k4 + 3) * 64 + c], acc2);
  }
  float y2 = acc2 + x1v;
  float t1 = wave_sum64(y2), t2 = wave_sum64(y2 * y2);
  float mean2 = t1 * 0.015625f, var2 = t2 * 0.015625f - mean2 * mean2;
  x_out[(size_t)row * 64 + c] =
      (y2 - mean2) * rsqrtf(var2 + EPS) * g2[c] + be2[c];
}

// K6: out = x @ W_fc + b_fc
__global__ __launch_bounds__(256) void k_head(
    const float* __restrict__ x, const float* __restrict__ Wfc,
    const float* __restrict__ bfc, float* __restrict__ out) {
  int gid = blockIdx.x * 256 + threadIdx.x;
  int r = gid >> 5, o = gid & 31;
  if (o >= 31) return;
  float acc = bfc[o];
  const float* xr = x + (size_t)r * 64;
#pragma unroll
  for (int i = 0; i < 64; ++i) acc = fmaf(xr[i], Wfc[i * 31 + o], acc);
  out[(size_t)r * 31 + o] = acc;
}

extern "C" void kernel_launch(void* const* d_in, const int* in_sizes, int n_in,
                              void* d_out, int out_size, void* d_ws, size_t ws_size,
                              hipStream_t stream) {
  const float* weather = (const float*)d_in[0];
  const float* coords  = (const float*)d_in[1];
  const int*   tidx    = (const int*)d_in[2];
  const float* W_emb   = (const float*)d_in[3];
  const float* b_emb   = (const float*)d_in[4];
  const float* W_qkv   = (const float*)d_in[5];
  const float* b_qkv   = (const float*)d_in[6];
  const float* W_out   = (const float*)d_in[7];
  const float* b_out   = (const float*)d_in[8];
  const float* gran    = (const float*)d_in[9];
  const float* g1      = (const float*)d_in[10];
  const float* be1     = (const float*)d_in[11];
  const float* W1      = (const float*)d_in[12];
  const float* b1      = (const float*)d_in[13];
  const float* W2      = (const float*)d_in[14];
  const float* b2      = (const float*)d_in[15];
  const float* g2      = (const float*)d_in[16];
  const float* be2     = (const float*)d_in[17];
  const float* W_fc    = (const float*)d_in[18];
  const float* b_fc    = (const float*)d_in[19];
  float* out = (float*)d_out;

  // workspace: x(2MB) | qb(1MB) | kb(1MB) | vt(1MB) | ao(2MB) = 7MB
  float* x = (float*)d_ws;
  unsigned int* qbw = (unsigned int*)(x + 8192 * 64);
  unsigned int* kbw = qbw + 64 * 1024 * 4;
  unsigned short* vtw = (unsigned short*)(kbw + 64 * 1024 * 4);
  float* ao = (float*)(vtw + 64 * 8 * 1024);

  k_embed<<<2048, 256, 0, stream>>>(weather, coords, W_emb, b_emb, x);
  for (int l = 0; l < 3; ++l) {
    k_qkv<<<1024, 192, 0, stream>>>(x, W_qkv + l * 64 * 192, b_qkv + l * 192,
                                    gran + l * 31 * 64, tidx, qbw, kbw, vtw);
    k_attn<<<512, 256, 0, stream>>>(qbw, kbw, vtw, ao);
    k_fused<<<2048, 256, 0, stream>>>(x, ao, W_out + l * 64 * 64, b_out + l * 64,
                                      g1 + l * 64, be1 + l * 64,
                                      W1 + l * 64 * 256, b1 + l * 256,
                                      W2 + l * 256 * 64, b2 + l * 64,
                                      g2 + l * 64, be2 + l * 64, x);
  }
  k_head<<<1024, 256, 0, stream>>>(x, W_fc, b_fc, out);
}

// Round 13
// 200.701 us; speedup vs baseline: 1.6336x; 1.3289x over previous
//
#include <hip/hip_runtime.h>
#include <math.h>

#define EPS 1e-5f

typedef float f32x16 __attribute__((ext_vector_type(16)));
typedef short short8 __attribute__((ext_vector_type(8)));

union U4S8 { uint4 u; short8 s; };

__device__ __forceinline__ float wave_sum64(float v) {
#pragma unroll
  for (int off = 32; off >= 1; off >>= 1) v += __shfl_xor(v, off, 64);
  return v;
}

__device__ __forceinline__ unsigned int bf16rne(float f) {
  unsigned int u = __float_as_uint(f);
  return (u + 0x7fffu + ((u >> 16) & 1u)) >> 16;
}
__device__ __forceinline__ unsigned int cvt_pk_bf16(float lo, float hi) {
  unsigned int r;
  asm("v_cvt_pk_bf16_f32 %0, %1, %2" : "=v"(r) : "v"(lo), "v"(hi));
  return r;
}

// K1: x = weather @ W_emb + b_emb + pos_encoding (4 rows/block)
__global__ __launch_bounds__(256) void k_embed(
    const float* __restrict__ weather, const float* __restrict__ coords,
    const float* __restrict__ W_emb, const float* __restrict__ b_emb,
    float* __restrict__ x) {
  int t = threadIdx.x, r = t >> 6, e = t & 63;
  int row = (blockIdx.x << 2) | r;  // b*1024 + s
  int b = row >> 10, s = row & 1023;
  __shared__ float wrow[4][32];
  if (e < 31) wrow[r][e] = weather[row * 31 + e];
  __syncthreads();
  float acc = b_emb[e];
#pragma unroll
  for (int i = 0; i < 31; ++i) acc = fmaf(wrow[r][i], W_emb[i * 64 + e], acc);
  int g = e >> 2, rem = e & 3;
  float div = __expf(-0.5756462732485115f * (float)g);
  float pe;
  if (rem == 0)      pe = sinf((float)s * div);
  else if (rem == 1) pe = cosf((float)s * div);
  else if (rem == 2) pe = sinf(coords[b * 2 + 0] * 0.017453292519943295f * div);
  else               pe = cosf(coords[b * 2 + 1] * 0.017453292519943295f * div);
  x[row * 64 + e] = acc + pe;
}

// K2: qkv projection into MFMA-attention layouts (all bf16):
//   qb[bh][s2][8 bf16]  = (q + gran) * 8^-0.5
//   kb[bh][s2][8 bf16]  = (k + gran)
//   vt[bh][d][1024 key] = v transposed
// bh = 8*(s%8)+h ; s2 = b*128 + s/8 ; hd = e%8.  8 rows/block, thread = col.
__global__ __launch_bounds__(192) void k_qkv(
    const float* __restrict__ x, const float* __restrict__ Wq,
    const float* __restrict__ bq, const float* __restrict__ gran,
    const int* __restrict__ tidx, unsigned int* __restrict__ qb,
    unsigned int* __restrict__ kbuf, unsigned short* __restrict__ vt) {
  int t = threadIdx.x;
  int row0 = blockIdx.x << 3;
  float acc[8];
  float bias = bq[t];
#pragma unroll
  for (int r = 0; r < 8; ++r) acc[r] = bias;
  const float* xp = x + (size_t)row0 * 64;
#pragma unroll 4
  for (int k4 = 0; k4 < 16; ++k4) {
    float4 xv[8];
#pragma unroll
    for (int r = 0; r < 8; ++r) xv[r] = *(const float4*)(xp + r * 64 + k4 * 4);
    float w0 = Wq[(4 * k4 + 0) * 192 + t];
    float w1 = Wq[(4 * k4 + 1) * 192 + t];
    float w2 = Wq[(4 * k4 + 2) * 192 + t];
    float w3 = Wq[(4 * k4 + 3) * 192 + t];
#pragma unroll
    for (int r = 0; r < 8; ++r) {
      acc[r] = fmaf(xv[r].x, w0, acc[r]);
      acc[r] = fmaf(xv[r].y, w1, acc[r]);
      acc[r] = fmaf(xv[r].z, w2, acc[r]);
      acc[r] = fmaf(xv[r].w, w3, acc[r]);
    }
  }
  int cq = t & 63;
  int hh = cq >> 3, hd = t & 7;
  int b = row0 >> 10, shi = (row0 & 1023) >> 3;
  int s2 = (b << 7) | shi;  // same for all 8 rows (row0 % 8 == 0)
  const float scl = 0.35355339059327373f;  // 8^-0.5 folded into q
#pragma unroll
  for (int r = 0; r < 8; ++r) {
    float o = acc[r];
    if (t < 128) o += gran[tidx[2 * r + 1] * 64 + cq];  // (row0+r)%8 == r
    int bh = (r << 3) | hh;
    if (t < 64) {
      o *= scl;
      float nb = __shfl_down(o, 1, 64);
      if ((hd & 1) == 0)
        qb[((((size_t)bh << 10) | s2) << 2) + (hd >> 1)] =
            bf16rne(o) | (bf16rne(nb) << 16);
    } else if (t < 128) {
      float nb = __shfl_down(o, 1, 64);
      if ((hd & 1) == 0)
        kbuf[((((size_t)bh << 10) | s2) << 2) + (hd >> 1)] =
            bf16rne(o) | (bf16rne(nb) << 16);
    } else {
      vt[((size_t)bh << 13) + (hd << 10) + s2] = (unsigned short)bf16rne(o);
    }
  }
}

// K3: MFMA flash attention (mfma_f32_32x32x16_bf16), no LDS. (round-12 kernel)
__global__ __launch_bounds__(256, 2) void k_attn(
    const unsigned int* __restrict__ qb, const unsigned int* __restrict__ kbuf,
    const unsigned short* __restrict__ vt, float* __restrict__ ao) {
  int bh = blockIdx.x >> 3, chunk = blockIdx.x & 7;
  int slo = bh >> 3, h = bh & 7;
  int t = threadIdx.x;
  int l = t & 63, w = t >> 6;
  int lq = l & 31, g = l >> 5;
  bool kl = (l < 32);     // real lanes for A(K) / B(Q) fragments
  bool vl = (lq < 8);     // real lanes for A(V^T) fragment (d = lq)
  int q = (chunk << 7) + (w << 5) + lq;  // this lane's query (s2 index)

  U4S8 qf;
  qf.u = make_uint4(0, 0, 0, 0);
  if (kl) qf.u = *(const uint4*)(qb + ((((size_t)bh << 10) + q) << 2));

  const uint4* kp = (const uint4*)(kbuf + ((size_t)bh << 12));
  const unsigned short* vp = vt + ((size_t)bh << 13);

  f32x16 O, Z;
#pragma unroll
  for (int i = 0; i < 16; ++i) { O[i] = 0.f; Z[i] = 0.f; }
  float m = -1e30f, ls = 0.f;

  for (int kblk = 0; kblk < 32; ++kblk) {  // 32 keys per iteration
    U4S8 af;
    af.u = make_uint4(0, 0, 0, 0);
    if (kl) af.u = kp[(kblk << 5) + lq];
    f32x16 S = __builtin_amdgcn_mfma_f32_32x32x16_bf16(af.s, qf.s, Z, 0, 0, 0);

    float mx = S[0];
#pragma unroll
    for (int i = 1; i < 16; ++i) mx = fmaxf(mx, S[i]);
    mx = fmaxf(mx, __shfl_xor(mx, 32, 64));  // shared max across lane pair
    if (mx > m + 8.f) {  // deferred-max cold path (always on first block)
      float esc = __expf(m - mx);
      ls *= esc;
      O *= esc;
      m = mx;
    }
    float p[16];
#pragma unroll
    for (int i = 0; i < 16; ++i) p[i] = __expf(S[i] - m);
    float s01 = (p[0] + p[1]) + (p[2] + p[3]);
    float s23 = (p[4] + p[5]) + (p[6] + p[7]);
    float s45 = (p[8] + p[9]) + (p[10] + p[11]);
    float s67 = (p[12] + p[13]) + (p[14] + p[15]);
    ls += (s01 + s23) + (s45 + s67);

    // pack P to bf16 pairs; key order per D-row map
    unsigned va = cvt_pk_bf16(p[0], p[1]),  vb = cvt_pk_bf16(p[2], p[3]);
    unsigned vc = cvt_pk_bf16(p[4], p[5]),  vd = cvt_pk_bf16(p[6], p[7]);
    unsigned ve = cvt_pk_bf16(p[8], p[9]),  vf = cvt_pk_bf16(p[10], p[11]);
    unsigned vg = cvt_pk_bf16(p[12], p[13]), vh = cvt_pk_bf16(p[14], p[15]);
    unsigned sa = __shfl_xor((int)va, 32, 64), sb = __shfl_xor((int)vb, 32, 64);
    unsigned sc = __shfl_xor((int)vc, 32, 64), sd = __shfl_xor((int)vd, 32, 64);
    unsigned se = __shfl_xor((int)ve, 32, 64), sf = __shfl_xor((int)vf, 32, 64);
    unsigned sg = __shfl_xor((int)vg, 32, 64), sh = __shfl_xor((int)vh, 32, 64);
    // B2 fragments (P^T): k-rows (lane>>5)*8+j
    U4S8 b1, b2;
    b1.u.x = kl ? va : sc;  b1.u.y = kl ? vb : sd;   // PV1: keys 0-15
    b1.u.z = kl ? sa : vc;  b1.u.w = kl ? sb : vd;
    b2.u.x = kl ? ve : sg;  b2.u.y = kl ? vf : sh;   // PV2: keys 16-31
    b2.u.z = kl ? se : vg;  b2.u.w = kl ? sf : vh;

    U4S8 v1, v2;
    v1.u = make_uint4(0, 0, 0, 0);
    v2.u = make_uint4(0, 0, 0, 0);
    if (vl) {  // A2 = V^T: row d=lq, keys kblk*32 + g*8 + j  (and +16)
      const unsigned short* vb8 = vp + (lq << 10) + (kblk << 5) + (g << 3);
      v1.u = *(const uint4*)vb8;
      v2.u = *(const uint4*)(vb8 + 16);
    }
    O = __builtin_amdgcn_mfma_f32_32x32x16_bf16(v1.s, b1.s, O, 0, 0, 0);
    O = __builtin_amdgcn_mfma_f32_32x32x16_bf16(v2.s, b2.s, O, 0, 0, 0);
  }

  ls += __shfl_xor(ls, 32, 64);  // pair partials share m -> plain add
  float inv = 1.0f / ls;
  // O regs 0-3 = O[d = 4g+reg][q]; write natural [b,s,e] layout
  int bq = q >> 7, sq = ((q & 127) << 3) | slo;
  float* op = ao + (((size_t)((bq << 10) | sq)) << 6) + (h << 3) + (g << 2);
  *(float4*)op = make_float4(O[0] * inv, O[1] * inv, O[2] * inv, O[3] * inv);
}

// K4 v2: fused  x = LN2( x1 + relu(x1@W1+b1)@W2+b2 ),  x1 = LN1( x + ao@Wo+bo )
// Round-12 lesson: 1 row/wave re-read Wo+W1+W2 (144 KB) per ROW -> L2-BW
// bound (VALUBusy 17%, ~34us of pure weight traffic). Now 4 rows/wave
// (16/block, grid 512): weight traffic /4, VALU ~2.5K instr/thread.
// Each wave touches only its own rows + LDS slices -> ZERO barriers.
__global__ __launch_bounds__(256, 2) void k_fused(
    const float* x_in, const float* __restrict__ ao,
    const float* __restrict__ Wo, const float* __restrict__ bo,
    const float* __restrict__ g1, const float* __restrict__ be1,
    const float* __restrict__ W1, const float* __restrict__ b1,
    const float* __restrict__ W2, const float* __restrict__ b2,
    const float* __restrict__ g2, const float* __restrict__ be2,
    float* x_out) {
  int t = threadIdx.x, w = t >> 6, c = t & 63;
  int ws = w << 2;
  int row0 = (blockIdx.x << 4) + ws;  // this wave's 4 rows
  __shared__ float aos[16][64];
  __shared__ float x1s[16][64];
  __shared__ float h1s[16][256];
  float xin[4];
#pragma unroll
  for (int r = 0; r < 4; ++r) {
    aos[ws + r][c] = ao[(size_t)(row0 + r) * 64 + c];
    xin[r] = x_in[(size_t)(row0 + r) * 64 + c];
  }
  // (no barrier anywhere: LDS regions are wave-private)
  // ---- proj + residual + LN1
  float acc[4];
  float bov = bo[c];
#pragma unroll
  for (int r = 0; r < 4; ++r) acc[r] = bov;
#pragma unroll 4
  for (int k4 = 0; k4 < 16; ++k4) {
    float w0 = Wo[(4 * k4 + 0) * 64 + c], w1 = Wo[(4 * k4 + 1) * 64 + c];
    float w2 = Wo[(4 * k4 + 2) * 64 + c], w3 = Wo[(4 * k4 + 3) * 64 + c];
#pragma unroll
    for (int r = 0; r < 4; ++r) {
      float4 av = *(const float4*)(&aos[ws + r][4 * k4]);
      acc[r] = fmaf(av.x, w0, acc[r]);
      acc[r] = fmaf(av.y, w1, acc[r]);
      acc[r] = fmaf(av.z, w2, acc[r]);
      acc[r] = fmaf(av.w, w3, acc[r]);
    }
  }
  float g1v = g1[c], be1v = be1[c];
  float x1v[4];
#pragma unroll
  for (int r = 0; r < 4; ++r) {
    float y = acc[r] + xin[r];
    float s1 = wave_sum64(y), s2 = wave_sum64(y * y);
    float mean = s1 * 0.015625f, var = s2 * 0.015625f - mean * mean;
    x1v[r] = (y - mean) * rsqrtf(var + EPS) * g1v + be1v;
    x1s[ws + r][c] = x1v[r];
  }
  // ---- ffn1: lane owns h1 cols 4c..4c+3 for the wave's 4 rows
  float4 h[4];
  float4 b1v = *(const float4*)(b1 + 4 * c);
#pragma unroll
  for (int r = 0; r < 4; ++r) h[r] = b1v;
#pragma unroll 4
  for (int k4 = 0; k4 < 16; ++k4) {
    float4 w0 = *(const float4*)(W1 + (size_t)(4 * k4 + 0) * 256 + 4 * c);
    float4 w1 = *(const float4*)(W1 + (size_t)(4 * k4 + 1) * 256 + 4 * c);
    float4 w2 = *(const float4*)(W1 + (size_t)(4 * k4 + 2) * 256 + 4 * c);
    float4 w3 = *(const float4*)(W1 + (size_t)(4 * k4 + 3) * 256 + 4 * c);
#pragma unroll
    for (int r = 0; r < 4; ++r) {
      float4 xv = *(const float4*)(&x1s[ws + r][4 * k4]);
      h[r].x = fmaf(xv.x, w0.x, h[r].x); h[r].y = fmaf(xv.x, w0.y, h[r].y);
      h[r].z = fmaf(xv.x, w0.z, h[r].z); h[r].w = fmaf(xv.x, w0.w, h[r].w);
      h[r].x = fmaf(xv.y, w1.x, h[r].x); h[r].y = fmaf(xv.y, w1.y, h[r].y);
      h[r].z = fmaf(xv.y, w1.z, h[r].z); h[r].w = fmaf(xv.y, w1.w, h[r].w);
      h[r].x = fmaf(xv.z, w2.x, h[r].x); h[r].y = fmaf(xv.z, w2.y, h[r].y);
      h[r].z = fmaf(xv.z, w2.z, h[r].z); h[r].w = fmaf(xv.z, w2.w, h[r].w);
      h[r].x = fmaf(xv.w, w3.x, h[r].x); h[r].y = fmaf(xv.w, w3.y, h[r].y);
      h[r].z = fmaf(xv.w, w3.z, h[r].z); h[r].w = fmaf(xv.w, w3.w, h[r].w);
    }
  }
#pragma unroll
  for (int r = 0; r < 4; ++r) {
    h[r].x = fmaxf(h[r].x, 0.f); h[r].y = fmaxf(h[r].y, 0.f);
    h[r].z = fmaxf(h[r].z, 0.f); h[r].w = fmaxf(h[r].w, 0.f);
    *(float4*)(&h1s[ws + r][4 * c]) = h[r];
  }
  // ---- ffn2
  float acc2[4];
  float b2v = b2[c];
#pragma unroll
  for (int r = 0; r < 4; ++r) acc2[r] = b2v;
#pragma unroll 4
  for (int k4 = 0; k4 < 64; ++k4) {
    float w0 = W2[(size_t)(4 * k4 + 0) * 64 + c];
    float w1 = W2[(size_t)(4 * k4 + 1) * 64 + c];
    float w2 = W2[(size_t)(4 * k4 + 2) * 64 + c];
    float w3 = W2[(size_t)(4 * k4 + 3) * 64 + c];
#pragma unroll
    for (int r = 0; r < 4; ++r) {
      float4 hv = *(const float4*)(&h1s[ws + r][4 * k4]);
      acc2[r] = fmaf(hv.x, w0, acc2[r]);
      acc2[r] = fmaf(hv.y, w1, acc2[r]);
      acc2[r] = fmaf(hv.z, w2, acc2[r]);
      acc2[r] = fmaf(hv.w, w3, acc2[r]);
    }
  }
  float g2v = g2[c], be2v = be2[c];
#pragma unroll
  for (int r = 0; r < 4; ++r) {
    float y2 = acc2[r] + x1v[r];
    float t1 = wave_sum64(y2), t2 = wave_sum64(y2 * y2);
    float mean2 = t1 * 0.015625f, var2 = t2 * 0.015625f - mean2 * mean2;
    x_out[(size_t)(row0 + r) * 64 + c] =
        (y2 - mean2) * rsqrtf(var2 + EPS) * g2v + be2v;
  }
}

// K6: out = x @ W_fc + b_fc
__global__ __launch_bounds__(256) void k_head(
    const float* __restrict__ x, const float* __restrict__ Wfc,
    const float* __restrict__ bfc, float* __restrict__ out) {
  int gid = blockIdx.x * 256 + threadIdx.x;
  int r = gid >> 5, o = gid & 31;
  if (o >= 31) return;
  float acc = bfc[o];
  const float* xr = x + (size_t)r * 64;
#pragma unroll
  for (int i = 0; i < 64; ++i) acc = fmaf(xr[i], Wfc[i * 31 + o], acc);
  out[(size_t)r * 31 + o] = acc;
}

extern "C" void kernel_launch(void* const* d_in, const int* in_sizes, int n_in,
                              void* d_out, int out_size, void* d_ws, size_t ws_size,
                              hipStream_t stream) {
  const float* weather = (const float*)d_in[0];
  const float* coords  = (const float*)d_in[1];
  const int*   tidx    = (const int*)d_in[2];
  const float* W_emb   = (const float*)d_in[3];
  const float* b_emb   = (const float*)d_in[4];
  const float* W_qkv   = (const float*)d_in[5];
  const float* b_qkv   = (const float*)d_in[6];
  const float* W_out   = (const float*)d_in[7];
  const float* b_out   = (const float*)d_in[8];
  const float* gran    = (const float*)d_in[9];
  const float* g1      = (const float*)d_in[10];
  const float* be1     = (const float*)d_in[11];
  const float* W1      = (const float*)d_in[12];
  const float* b1      = (const float*)d_in[13];
  const float* W2      = (const float*)d_in[14];
  const float* b2      = (const float*)d_in[15];
  const float* g2      = (const float*)d_in[16];
  const float* be2     = (const float*)d_in[17];
  const float* W_fc    = (const float*)d_in[18];
  const float* b_fc    = (const float*)d_in[19];
  float* out = (float*)d_out;

  // workspace: x(2MB) | qb(1MB) | kb(1MB) | vt(1MB) | ao(2MB) = 7MB
  float* x = (float*)d_ws;
  unsigned int* qbw = (unsigned int*)(x + 8192 * 64);
  unsigned int* kbw = qbw + 64 * 1024 * 4;
  unsigned short* vtw = (unsigned short*)(kbw + 64 * 1024 * 4);
  float* ao = (float*)(vtw + 64 * 8 * 1024);

  k_embed<<<2048, 256, 0, stream>>>(weather, coords, W_emb, b_emb, x);
  for (int l = 0; l < 3; ++l) {
    k_qkv<<<1024, 192, 0, stream>>>(x, W_qkv + l * 64 * 192, b_qkv + l * 192,
                                    gran + l * 31 * 64, tidx, qbw, kbw, vtw);
    k_attn<<<512, 256, 0, stream>>>(qbw, kbw, vtw, ao);
    k_fused<<<512, 256, 0, stream>>>(x, ao, W_out + l * 64 * 64, b_out + l * 64,
                                     g1 + l * 64, be1 + l * 64,
                                     W1 + l * 64 * 256, b1 + l * 256,
                                     W2 + l * 256 * 64, b2 + l * 64,
                                     g2 + l * 64, be2 + l * 64, x);
  }
  k_head<<<1024, 256, 0, stream>>>(x, W_fc, b_fc, out);
}

// Round 14
// 184.036 us; speedup vs baseline: 1.7815x; 1.0906x over previous
//
#include <hip/hip_runtime.h>
#include <math.h>

#define EPS 1e-5f

typedef float f32x16 __attribute__((ext_vector_type(16)));
typedef short short8 __attribute__((ext_vector_type(8)));

union U4S8 { uint4 u; short8 s; };

__device__ __forceinline__ float wave_sum64(float v) {
#pragma unroll
  for (int off = 32; off >= 1; off >>= 1) v += __shfl_xor(v, off, 64);
  return v;
}

__device__ __forceinline__ unsigned int bf16rne(float f) {
  unsigned int u = __float_as_uint(f);
  return (u + 0x7fffu + ((u >> 16) & 1u)) >> 16;
}
__device__ __forceinline__ unsigned int cvt_pk_bf16(float lo, float hi) {
  unsigned int r;
  asm("v_cvt_pk_bf16_f32 %0, %1, %2" : "=v"(r) : "v"(lo), "v"(hi));
  return r;
}

// K1: x = weather @ W_emb + b_emb + pos_encoding (4 rows/block)
__global__ __launch_bounds__(256) void k_embed(
    const float* __restrict__ weather, const float* __restrict__ coords,
    const float* __restrict__ W_emb, const float* __restrict__ b_emb,
    float* __restrict__ x) {
  int t = threadIdx.x, r = t >> 6, e = t & 63;
  int row = (blockIdx.x << 2) | r;  // b*1024 + s
  int b = row >> 10, s = row & 1023;
  __shared__ float wrow[4][32];
  if (e < 31) wrow[r][e] = weather[row * 31 + e];
  __syncthreads();
  float acc = b_emb[e];
#pragma unroll
  for (int i = 0; i < 31; ++i) acc = fmaf(wrow[r][i], W_emb[i * 64 + e], acc);
  int g = e >> 2, rem = e & 3;
  float div = __expf(-0.5756462732485115f * (float)g);
  float pe;
  if (rem == 0)      pe = sinf((float)s * div);
  else if (rem == 1) pe = cosf((float)s * div);
  else if (rem == 2) pe = sinf(coords[b * 2 + 0] * 0.017453292519943295f * div);
  else               pe = cosf(coords[b * 2 + 1] * 0.017453292519943295f * div);
  x[row * 64 + e] = acc + pe;
}

// K2: qkv projection into MFMA-attention layouts (all bf16):
//   qb[bh][s2][8 bf16]  = (q + gran) * 8^-0.5
//   kb[bh][s2][8 bf16]  = (k + gran)
//   vt[bh][d][1024 key] = v transposed
__global__ __launch_bounds__(192) void k_qkv(
    const float* __restrict__ x, const float* __restrict__ Wq,
    const float* __restrict__ bq, const float* __restrict__ gran,
    const int* __restrict__ tidx, unsigned int* __restrict__ qb,
    unsigned int* __restrict__ kbuf, unsigned short* __restrict__ vt) {
  int t = threadIdx.x;
  int row0 = blockIdx.x << 3;
  float acc[8];
  float bias = bq[t];
#pragma unroll
  for (int r = 0; r < 8; ++r) acc[r] = bias;
  const float* xp = x + (size_t)row0 * 64;
#pragma unroll 4
  for (int k4 = 0; k4 < 16; ++k4) {
    float4 xv[8];
#pragma unroll
    for (int r = 0; r < 8; ++r) xv[r] = *(const float4*)(xp + r * 64 + k4 * 4);
    float w0 = Wq[(4 * k4 + 0) * 192 + t];
    float w1 = Wq[(4 * k4 + 1) * 192 + t];
    float w2 = Wq[(4 * k4 + 2) * 192 + t];
    float w3 = Wq[(4 * k4 + 3) * 192 + t];
#pragma unroll
    for (int r = 0; r < 8; ++r) {
      acc[r] = fmaf(xv[r].x, w0, acc[r]);
      acc[r] = fmaf(xv[r].y, w1, acc[r]);
      acc[r] = fmaf(xv[r].z, w2, acc[r]);
      acc[r] = fmaf(xv[r].w, w3, acc[r]);
    }
  }
  int cq = t & 63;
  int hh = cq >> 3, hd = t & 7;
  int b = row0 >> 10, shi = (row0 & 1023) >> 3;
  int s2 = (b << 7) | shi;  // same for all 8 rows (row0 % 8 == 0)
  const float scl = 0.35355339059327373f;  // 8^-0.5 folded into q
#pragma unroll
  for (int r = 0; r < 8; ++r) {
    float o = acc[r];
    if (t < 128) o += gran[tidx[2 * r + 1] * 64 + cq];  // (row0+r)%8 == r
    int bh = (r << 3) | hh;
    if (t < 64) {
      o *= scl;
      float nb = __shfl_down(o, 1, 64);
      if ((hd & 1) == 0)
        qb[((((size_t)bh << 10) | s2) << 2) + (hd >> 1)] =
            bf16rne(o) | (bf16rne(nb) << 16);
    } else if (t < 128) {
      float nb = __shfl_down(o, 1, 64);
      if ((hd & 1) == 0)
        kbuf[((((size_t)bh << 10) | s2) << 2) + (hd >> 1)] =
            bf16rne(o) | (bf16rne(nb) << 16);
    } else {
      vt[((size_t)bh << 13) + (hd << 10) + s2] = (unsigned short)bf16rne(o);
    }
  }
}

// K3 v2: MFMA flash attention, split-K x2 in-block.
// Block = 512 threads = 8 waves = 4 query-groups x 2 key-halves; each wave
// runs 16 of 32 key-blocks (round-13 lesson: 2048 waves = 2/SIMD was
// latency-bound on the per-iter MFMA->softmax->pack chain; now 4096 waves).
// Partials (m, ls, O[0..3]) merged via 6KB LDS + one barrier; merge math is
// exact (partials are sums of exp(s - m), m a reference point).
__global__ __launch_bounds__(512, 2) void k_attn(
    const unsigned int* __restrict__ qb, const unsigned int* __restrict__ kbuf,
    const unsigned short* __restrict__ vt, float* __restrict__ ao) {
  int bh = blockIdx.x >> 3, chunk = blockIdx.x & 7;
  int slo = bh >> 3, h = bh & 7;
  int t = threadIdx.x;
  int l = t & 63, w = t >> 6;
  int grp = w >> 1, kh = w & 1;  // query group 0..3, key half 0..1
  int lq = l & 31, g = l >> 5;
  bool kl = (l < 32);     // real lanes for A(K) / B(Q) fragments
  bool vl = (lq < 8);     // real lanes for A(V^T) fragment (d = lq)
  int q = (chunk << 7) + (grp << 5) + lq;  // this lane's query (s2 index)

  U4S8 qf;
  qf.u = make_uint4(0, 0, 0, 0);
  if (kl) qf.u = *(const uint4*)(qb + ((((size_t)bh << 10) + q) << 2));

  const uint4* kp = (const uint4*)(kbuf + ((size_t)bh << 12));
  const unsigned short* vp = vt + ((size_t)bh << 13);

  f32x16 O, Z;
#pragma unroll
  for (int i = 0; i < 16; ++i) { O[i] = 0.f; Z[i] = 0.f; }
  float m = -1e30f, ls = 0.f;

  int kb0 = kh << 4;
  for (int kblk = kb0; kblk < kb0 + 16; ++kblk) {  // 32 keys per iteration
    U4S8 af;
    af.u = make_uint4(0, 0, 0, 0);
    if (kl) af.u = kp[(kblk << 5) + lq];
    f32x16 S = __builtin_amdgcn_mfma_f32_32x32x16_bf16(af.s, qf.s, Z, 0, 0, 0);

    float mx = S[0];
#pragma unroll
    for (int i = 1; i < 16; ++i) mx = fmaxf(mx, S[i]);
    mx = fmaxf(mx, __shfl_xor(mx, 32, 64));  // shared max across lane pair
    if (mx > m + 8.f) {  // deferred-max cold path
      float esc = __expf(m - mx);
      ls *= esc;
      O *= esc;
      m = mx;
    }
    float p[16];
#pragma unroll
    for (int i = 0; i < 16; ++i) p[i] = __expf(S[i] - m);
    float s01 = (p[0] + p[1]) + (p[2] + p[3]);
    float s23 = (p[4] + p[5]) + (p[6] + p[7]);
    float s45 = (p[8] + p[9]) + (p[10] + p[11]);
    float s67 = (p[12] + p[13]) + (p[14] + p[15]);
    ls += (s01 + s23) + (s45 + s67);

    unsigned va = cvt_pk_bf16(p[0], p[1]),  vb = cvt_pk_bf16(p[2], p[3]);
    unsigned vc = cvt_pk_bf16(p[4], p[5]),  vd = cvt_pk_bf16(p[6], p[7]);
    unsigned ve = cvt_pk_bf16(p[8], p[9]),  vf = cvt_pk_bf16(p[10], p[11]);
    unsigned vg = cvt_pk_bf16(p[12], p[13]), vh = cvt_pk_bf16(p[14], p[15]);
    unsigned sa = __shfl_xor((int)va, 32, 64), sb = __shfl_xor((int)vb, 32, 64);
    unsigned sc = __shfl_xor((int)vc, 32, 64), sd = __shfl_xor((int)vd, 32, 64);
    unsigned se = __shfl_xor((int)ve, 32, 64), sf = __shfl_xor((int)vf, 32, 64);
    unsigned sg = __shfl_xor((int)vg, 32, 64), sh = __shfl_xor((int)vh, 32, 64);
    U4S8 b1, b2;
    b1.u.x = kl ? va : sc;  b1.u.y = kl ? vb : sd;   // PV1: keys 0-15
    b1.u.z = kl ? sa : vc;  b1.u.w = kl ? sb : vd;
    b2.u.x = kl ? ve : sg;  b2.u.y = kl ? vf : sh;   // PV2: keys 16-31
    b2.u.z = kl ? se : vg;  b2.u.w = kl ? sf : vh;

    U4S8 v1, v2;
    v1.u = make_uint4(0, 0, 0, 0);
    v2.u = make_uint4(0, 0, 0, 0);
    if (vl) {
      const unsigned short* vb8 = vp + (lq << 10) + (kblk << 5) + (g << 3);
      v1.u = *(const uint4*)vb8;
      v2.u = *(const uint4*)(vb8 + 16);
    }
    O = __builtin_amdgcn_mfma_f32_32x32x16_bf16(v1.s, b1.s, O, 0, 0, 0);
    O = __builtin_amdgcn_mfma_f32_32x32x16_bf16(v2.s, b2.s, O, 0, 0, 0);
  }

  ls += __shfl_xor(ls, 32, 64);  // pair partials share m -> plain add

  // cross-wave merge: key-half 0 stores partials, key-half 1 merges+writes
  __shared__ float pm[4][64], pl[4][64];
  __shared__ float po[4][64][4];
  if (kh == 0) {
    pm[grp][l] = m;
    pl[grp][l] = ls;
    *(float4*)(&po[grp][l][0]) = make_float4(O[0], O[1], O[2], O[3]);
  }
  __syncthreads();
  if (kh == 1) {
    float mA = pm[grp][l], lsA = pl[grp][l];
    float nm = fmaxf(m, mA);
    float wB = __expf(m - nm), wA = __expf(mA - nm);
    float4 oA = *(const float4*)(&po[grp][l][0]);
    float inv = 1.0f / (ls * wB + lsA * wA);
    int bq = q >> 7, sq = ((q & 127) << 3) | slo;
    float* op = ao + (((size_t)((bq << 10) | sq)) << 6) + (h << 3) + (g << 2);
    *(float4*)op = make_float4((O[0] * wB + oA.x * wA) * inv,
                               (O[1] * wB + oA.y * wA) * inv,
                               (O[2] * wB + oA.z * wA) * inv,
                               (O[3] * wB + oA.w * wA) * inv);
  }
}

// K4 v3: fused residual+LN+FFN+LN, 4 rows/wave, 16 rows/block.
// Round-13 lesson: ffn2's 256 stride-32 global W2 loads were the latency
// bottleneck (VGPR=40 -> compiler interleaves load-use, ~200-400cy each).
// W2 now staged ONCE per block into LDS as packed bf16 (32KB; total LDS
// 56KB -> still 2 blocks/CU). Staging loads issue first and drain at the
// single barrier; ffn2 reads become 2-way-free ds_read_b32 + shift/mask.
__global__ __launch_bounds__(256, 2) void k_fused(
    const float* x_in, const float* __restrict__ ao,
    const float* __restrict__ Wo, const float* __restrict__ bo,
    const float* __restrict__ g1, const float* __restrict__ be1,
    const float* __restrict__ W1, const float* __restrict__ b1,
    const float* __restrict__ W2, const float* __restrict__ b2,
    const float* __restrict__ g2, const float* __restrict__ be2,
    float* x_out) {
  int t = threadIdx.x, w = t >> 6, c = t & 63;
  int ws = w << 2;
  int row0 = (blockIdx.x << 4) + ws;  // this wave's 4 rows
  __shared__ unsigned int w2b[8192];  // W2 as bf16 pairs, 32KB
  __shared__ float aos[16][64];
  __shared__ float x1s[16][64];
  __shared__ float h1s[16][256];
  // stage W2 (issue early; completes by the barrier below)
  for (int i = t; i < 8192; i += 256) {
    float2 f = *(const float2*)(W2 + 2 * i);
    w2b[i] = bf16rne(f.x) | (bf16rne(f.y) << 16);
  }
  float xin[4];
#pragma unroll
  for (int r = 0; r < 4; ++r) {
    aos[ws + r][c] = ao[(size_t)(row0 + r) * 64 + c];
    xin[r] = x_in[(size_t)(row0 + r) * 64 + c];
  }
  // ---- proj + residual + LN1 (Wo fp32 from global)
  float acc[4];
  float bov = bo[c];
#pragma unroll
  for (int r = 0; r < 4; ++r) acc[r] = bov;
#pragma unroll 4
  for (int k4 = 0; k4 < 16; ++k4) {
    float w0 = Wo[(4 * k4 + 0) * 64 + c], w1 = Wo[(4 * k4 + 1) * 64 + c];
    float w2 = Wo[(4 * k4 + 2) * 64 + c], w3 = Wo[(4 * k4 + 3) * 64 + c];
#pragma unroll
    for (int r = 0; r < 4; ++r) {
      float4 av = *(const float4*)(&aos[ws + r][4 * k4]);
      acc[r] = fmaf(av.x, w0, acc[r]);
      acc[r] = fmaf(av.y, w1, acc[r]);
      acc[r] = fmaf(av.z, w2, acc[r]);
      acc[r] = fmaf(av.w, w3, acc[r]);
    }
  }
  float g1v = g1[c], be1v = be1[c];
  float x1v[4];
#pragma unroll
  for (int r = 0; r < 4; ++r) {
    float y = acc[r] + xin[r];
    float s1 = wave_sum64(y), s2 = wave_sum64(y * y);
    float mean = s1 * 0.015625f, var = s2 * 0.015625f - mean * mean;
    x1v[r] = (y - mean) * rsqrtf(var + EPS) * g1v + be1v;
    x1s[ws + r][c] = x1v[r];
  }
  // ---- ffn1 (W1 fp32 from global): lane owns h1 cols 4c..4c+3
  float4 h[4];
  float4 b1v = *(const float4*)(b1 + 4 * c);
#pragma unroll
  for (int r = 0; r < 4; ++r) h[r] = b1v;
#pragma unroll 4
  for (int k4 = 0; k4 < 16; ++k4) {
    float4 w0 = *(const float4*)(W1 + (size_t)(4 * k4 + 0) * 256 + 4 * c);
    float4 w1 = *(const float4*)(W1 + (size_t)(4 * k4 + 1) * 256 + 4 * c);
    float4 w2 = *(const float4*)(W1 + (size_t)(4 * k4 + 2) * 256 + 4 * c);
    float4 w3 = *(const float4*)(W1 + (size_t)(4 * k4 + 3) * 256 + 4 * c);
#pragma unroll
    for (int r = 0; r < 4; ++r) {
      float4 xv = *(const float4*)(&x1s[ws + r][4 * k4]);
      h[r].x = fmaf(xv.x, w0.x, h[r].x); h[r].y = fmaf(xv.x, w0.y, h[r].y);
      h[r].z = fmaf(xv.x, w0.z, h[r].z); h[r].w = fmaf(xv.x, w0.w, h[r].w);
      h[r].x = fmaf(xv.y, w1.x, h[r].x); h[r].y = fmaf(xv.y, w1.y, h[r].y);
      h[r].z = fmaf(xv.y, w1.z, h[r].z); h[r].w = fmaf(xv.y, w1.w, h[r].w);
      h[r].x = fmaf(xv.z, w2.x, h[r].x); h[r].y = fmaf(xv.z, w2.y, h[r].y);
      h[r].z = fmaf(xv.z, w2.z, h[r].z); h[r].w = fmaf(xv.z, w2.w, h[r].w);
      h[r].x = fmaf(xv.w, w3.x, h[r].x); h[r].y = fmaf(xv.w, w3.y, h[r].y);
      h[r].z = fmaf(xv.w, w3.z, h[r].z); h[r].w = fmaf(xv.w, w3.w, h[r].w);
    }
  }
#pragma unroll
  for (int r = 0; r < 4; ++r) {
    h[r].x = fmaxf(h[r].x, 0.f); h[r].y = fmaxf(h[r].y, 0.f);
    h[r].z = fmaxf(h[r].z, 0.f); h[r].w = fmaxf(h[r].w, 0.f);
    *(float4*)(&h1s[ws + r][4 * c]) = h[r];
  }
  __syncthreads();  // W2 staging complete (and wave-private h1s written)
  // ---- ffn2 from LDS bf16
  int sh = (c & 1) ? 0 : 16;
  int wbase = c >> 1;
  float acc2[4];
  float b2v = b2[c];
#pragma unroll
  for (int r = 0; r < 4; ++r) acc2[r] = b2v;
#pragma unroll 4
  for (int k4 = 0; k4 < 64; ++k4) {
    float w0 = __uint_as_float((w2b[(4 * k4 + 0) * 32 + wbase] << sh) & 0xffff0000u);
    float w1 = __uint_as_float((w2b[(4 * k4 + 1) * 32 + wbase] << sh) & 0xffff0000u);
    float w2 = __uint_as_float((w2b[(4 * k4 + 2) * 32 + wbase] << sh) & 0xffff0000u);
    float w3 = __uint_as_float((w2b[(4 * k4 + 3) * 32 + wbase] << sh) & 0xffff0000u);
#pragma unroll
    for (int r = 0; r < 4; ++r) {
      float4 hv = *(const float4*)(&h1s[ws + r][4 * k4]);
      acc2[r] = fmaf(hv.x, w0, acc2[r]);
      acc2[r] = fmaf(hv.y, w1, acc2[r]);
      acc2[r] = fmaf(hv.z, w2, acc2[r]);
      acc2[r] = fmaf(hv.w, w3, acc2[r]);
    }
  }
  float g2v = g2[c], be2v = be2[c];
#pragma unroll
  for (int r = 0; r < 4; ++r) {
    float y2 = acc2[r] + x1v[r];
    float t1 = wave_sum64(y2), t2 = wave_sum64(y2 * y2);
    float mean2 = t1 * 0.015625f, var2 = t2 * 0.015625f - mean2 * mean2;
    x_out[(size_t)(row0 + r) * 64 + c] =
        (y2 - mean2) * rsqrtf(var2 + EPS) * g2v + be2v;
  }
}

// K6: out = x @ W_fc + b_fc
__global__ __launch_bounds__(256) void k_head(
    const float* __restrict__ x, const float* __restrict__ Wfc,
    const float* __restrict__ bfc, float* __restrict__ out) {
  int gid = blockIdx.x * 256 + threadIdx.x;
  int r = gid >> 5, o = gid & 31;
  if (o >= 31) return;
  float acc = bfc[o];
  const float* xr = x + (size_t)r * 64;
#pragma unroll
  for (int i = 0; i < 64; ++i) acc = fmaf(xr[i], Wfc[i * 31 + o], acc);
  out[(size_t)r * 31 + o] = acc;
}

extern "C" void kernel_launch(void* const* d_in, const int* in_sizes, int n_in,
                              void* d_out, int out_size, void* d_ws, size_t ws_size,
                              hipStream_t stream) {
  const float* weather = (const float*)d_in[0];
  const float* coords  = (const float*)d_in[1];
  const int*   tidx    = (const int*)d_in[2];
  const float* W_emb   = (const float*)d_in[3];
  const float* b_emb   = (const float*)d_in[4];
  const float* W_qkv   = (const float*)d_in[5];
  const float* b_qkv   = (const float*)d_in[6];
  const float* W_out   = (const float*)d_in[7];
  const float* b_out   = (const float*)d_in[8];
  const float* gran    = (const float*)d_in[9];
  const float* g1      = (const float*)d_in[10];
  const float* be1     = (const float*)d_in[11];
  const float* W1      = (const float*)d_in[12];
  const float* b1      = (const float*)d_in[13];
  const float* W2      = (const float*)d_in[14];
  const float* b2      = (const float*)d_in[15];
  const float* g2      = (const float*)d_in[16];
  const float* be2     = (const float*)d_in[17];
  const float* W_fc    = (const float*)d_in[18];
  const float* b_fc    = (const float*)d_in[19];
  float* out = (float*)d_out;

  // workspace: x(2MB) | qb(1MB) | kb(1MB) | vt(1MB) | ao(2MB) = 7MB
  float* x = (float*)d_ws;
  unsigned int* qbw = (unsigned int*)(x + 8192 * 64);
  unsigned int* kbw = qbw + 64 * 1024 * 4;
  unsigned short* vtw = (unsigned short*)(kbw + 64 * 1024 * 4);
  float* ao = (float*)(vtw + 64 * 8 * 1024);

  k_embed<<<2048, 256, 0, stream>>>(weather, coords, W_emb, b_emb, x);
  for (int l = 0; l < 3; ++l) {
    k_qkv<<<1024, 192, 0, stream>>>(x, W_qkv + l * 64 * 192, b_qkv + l * 192,
                                    gran + l * 31 * 64, tidx, qbw, kbw, vtw);
    k_attn<<<512, 512, 0, stream>>>(qbw, kbw, vtw, ao);
    k_fused<<<512, 256, 0, stream>>>(x, ao, W_out + l * 64 * 64, b_out + l * 64,
                                     g1 + l * 64, be1 + l * 64,
                                     W1 + l * 64 * 256, b1 + l * 256,
                                     W2 + l * 256 * 64, b2 + l * 64,
                                     g2 + l * 64, be2 + l * 64, x);
  }
  k_head<<<1024, 256, 0, stream>>>(x, W_fc, b_fc, out);
}

// Round 16
// 175.443 us; speedup vs baseline: 1.8688x; 1.0490x over previous
//
#include <hip/hip_runtime.h>
#include <math.h>

#define EPS 1e-5f

typedef float f32x16 __attribute__((ext_vector_type(16)));
typedef short short8 __attribute__((ext_vector_type(8)));

union U4S8 { uint4 u; short8 s; };

__device__ __forceinline__ float wave_sum64(float v) {
#pragma unroll
  for (int off = 32; off >= 1; off >>= 1) v += __shfl_xor(v, off, 64);
  return v;
}

__device__ __forceinline__ unsigned int bf16rne(float f) {
  unsigned int u = __float_as_uint(f);
  return (u + 0x7fffu + ((u >> 16) & 1u)) >> 16;
}
__device__ __forceinline__ unsigned int cvt_pk_bf16(float lo, float hi) {
  unsigned int r;
  asm("v_cvt_pk_bf16_f32 %0, %1, %2" : "=v"(r) : "v"(lo), "v"(hi));
  return r;
}

// K0: embed (x = weather@W_emb + pe) + qkv projection for layer 0, fused.
// 8 rows/block, 192 threads. Phase A computes x rows into LDS + global;
// phase B is the round-14 k_qkv body reading x from LDS (bit-identical).
// ROUND-15 BUG FIX: staging loop bound was 248 with stride-32 indexing,
// leaving wrow[7][24..30] uninitialized (poisoned LDS -> NaN). Bound = 256.
__global__ __launch_bounds__(192) void k_qkv0(
    const float* __restrict__ weather, const float* __restrict__ coords,
    const float* __restrict__ W_emb, const float* __restrict__ b_emb,
    const float* __restrict__ Wq, const float* __restrict__ bq,
    const float* __restrict__ gran, const int* __restrict__ tidx,
    float* __restrict__ x, unsigned int* __restrict__ qb,
    unsigned int* __restrict__ kbuf, unsigned short* __restrict__ vt) {
  int t = threadIdx.x;
  int row0 = blockIdx.x << 3;
  __shared__ float wrow[8][32];
  __shared__ float xs[8][64];
  for (int i = t; i < 256; i += 192) {
    int r = i >> 5, c2 = i & 31;
    if (c2 < 31) wrow[r][c2] = weather[(size_t)(row0 + r) * 31 + c2];
  }
  __syncthreads();
  int b = row0 >> 10;
  float lat = coords[b * 2 + 0] * 0.017453292519943295f;
  float lon = coords[b * 2 + 1] * 0.017453292519943295f;
  for (int idx = t; idx < 512; idx += 192) {
    int r = idx >> 6, e = idx & 63;
    int s = (row0 + r) & 1023;
    float acc = b_emb[e];
#pragma unroll
    for (int i = 0; i < 31; ++i) acc = fmaf(wrow[r][i], W_emb[i * 64 + e], acc);
    int g = e >> 2, rem = e & 3;
    float div = __expf(-0.5756462732485115f * (float)g);
    float pe;
    if (rem == 0)      pe = sinf((float)s * div);
    else if (rem == 1) pe = cosf((float)s * div);
    else if (rem == 2) pe = sinf(lat * div);
    else               pe = cosf(lon * div);
    float xv = acc + pe;
    xs[r][e] = xv;
    x[(size_t)(row0 + r) * 64 + e] = xv;
  }
  __syncthreads();
  // ---- qkv phase (reads xs from LDS)
  float acc[8];
  float bias = bq[t];
#pragma unroll
  for (int r = 0; r < 8; ++r) acc[r] = bias;
#pragma unroll 4
  for (int k4 = 0; k4 < 16; ++k4) {
    float4 xv[8];
#pragma unroll
    for (int r = 0; r < 8; ++r) xv[r] = *(const float4*)(&xs[r][4 * k4]);
    float w0 = Wq[(4 * k4 + 0) * 192 + t];
    float w1 = Wq[(4 * k4 + 1) * 192 + t];
    float w2 = Wq[(4 * k4 + 2) * 192 + t];
    float w3 = Wq[(4 * k4 + 3) * 192 + t];
#pragma unroll
    for (int r = 0; r < 8; ++r) {
      acc[r] = fmaf(xv[r].x, w0, acc[r]);
      acc[r] = fmaf(xv[r].y, w1, acc[r]);
      acc[r] = fmaf(xv[r].z, w2, acc[r]);
      acc[r] = fmaf(xv[r].w, w3, acc[r]);
    }
  }
  int cq = t & 63;
  int hh = cq >> 3, hd = t & 7;
  int shi = (row0 & 1023) >> 3;
  int s2 = (b << 7) | shi;
  const float scl = 0.35355339059327373f;
#pragma unroll
  for (int r = 0; r < 8; ++r) {
    float o = acc[r];
    if (t < 128) o += gran[tidx[2 * r + 1] * 64 + cq];
    int bh = (r << 3) | hh;
    if (t < 64) {
      o *= scl;
      float nb = __shfl_down(o, 1, 64);
      if ((hd & 1) == 0)
        qb[((((size_t)bh << 10) | s2) << 2) + (hd >> 1)] =
            bf16rne(o) | (bf16rne(nb) << 16);
    } else if (t < 128) {
      float nb = __shfl_down(o, 1, 64);
      if ((hd & 1) == 0)
        kbuf[((((size_t)bh << 10) | s2) << 2) + (hd >> 1)] =
            bf16rne(o) | (bf16rne(nb) << 16);
    } else {
      vt[((size_t)bh << 13) + (hd << 10) + s2] = (unsigned short)bf16rne(o);
    }
  }
}

// K3 v2: MFMA flash attention, split-K x2 in-block (round-14 kernel).
__global__ __launch_bounds__(512, 2) void k_attn(
    const unsigned int* __restrict__ qb, const unsigned int* __restrict__ kbuf,
    const unsigned short* __restrict__ vt, float* __restrict__ ao) {
  int bh = blockIdx.x >> 3, chunk = blockIdx.x & 7;
  int slo = bh >> 3, h = bh & 7;
  int t = threadIdx.x;
  int l = t & 63, w = t >> 6;
  int grp = w >> 1, kh = w & 1;
  int lq = l & 31, g = l >> 5;
  bool kl = (l < 32);
  bool vl = (lq < 8);
  int q = (chunk << 7) + (grp << 5) + lq;

  U4S8 qf;
  qf.u = make_uint4(0, 0, 0, 0);
  if (kl) qf.u = *(const uint4*)(qb + ((((size_t)bh << 10) + q) << 2));

  const uint4* kp = (const uint4*)(kbuf + ((size_t)bh << 12));
  const unsigned short* vp = vt + ((size_t)bh << 13);

  f32x16 O, Z;
#pragma unroll
  for (int i = 0; i < 16; ++i) { O[i] = 0.f; Z[i] = 0.f; }
  float m = -1e30f, ls = 0.f;

  int kb0 = kh << 4;
  for (int kblk = kb0; kblk < kb0 + 16; ++kblk) {
    U4S8 af;
    af.u = make_uint4(0, 0, 0, 0);
    if (kl) af.u = kp[(kblk << 5) + lq];
    f32x16 S = __builtin_amdgcn_mfma_f32_32x32x16_bf16(af.s, qf.s, Z, 0, 0, 0);

    float mx = S[0];
#pragma unroll
    for (int i = 1; i < 16; ++i) mx = fmaxf(mx, S[i]);
    mx = fmaxf(mx, __shfl_xor(mx, 32, 64));
    if (mx > m + 8.f) {
      float esc = __expf(m - mx);
      ls *= esc;
      O *= esc;
      m = mx;
    }
    float p[16];
#pragma unroll
    for (int i = 0; i < 16; ++i) p[i] = __expf(S[i] - m);
    float s01 = (p[0] + p[1]) + (p[2] + p[3]);
    float s23 = (p[4] + p[5]) + (p[6] + p[7]);
    float s45 = (p[8] + p[9]) + (p[10] + p[11]);
    float s67 = (p[12] + p[13]) + (p[14] + p[15]);
    ls += (s01 + s23) + (s45 + s67);

    unsigned va = cvt_pk_bf16(p[0], p[1]),  vb = cvt_pk_bf16(p[2], p[3]);
    unsigned vc = cvt_pk_bf16(p[4], p[5]),  vd = cvt_pk_bf16(p[6], p[7]);
    unsigned ve = cvt_pk_bf16(p[8], p[9]),  vf = cvt_pk_bf16(p[10], p[11]);
    unsigned vg = cvt_pk_bf16(p[12], p[13]), vh = cvt_pk_bf16(p[14], p[15]);
    unsigned sa = __shfl_xor((int)va, 32, 64), sb = __shfl_xor((int)vb, 32, 64);
    unsigned sc = __shfl_xor((int)vc, 32, 64), sd = __shfl_xor((int)vd, 32, 64);
    unsigned se = __shfl_xor((int)ve, 32, 64), sf = __shfl_xor((int)vf, 32, 64);
    unsigned sg = __shfl_xor((int)vg, 32, 64), sh = __shfl_xor((int)vh, 32, 64);
    U4S8 b1, b2;
    b1.u.x = kl ? va : sc;  b1.u.y = kl ? vb : sd;
    b1.u.z = kl ? sa : vc;  b1.u.w = kl ? sb : vd;
    b2.u.x = kl ? ve : sg;  b2.u.y = kl ? vf : sh;
    b2.u.z = kl ? se : vg;  b2.u.w = kl ? sf : vh;

    U4S8 v1, v2;
    v1.u = make_uint4(0, 0, 0, 0);
    v2.u = make_uint4(0, 0, 0, 0);
    if (vl) {
      const unsigned short* vb8 = vp + (lq << 10) + (kblk << 5) + (g << 3);
      v1.u = *(const uint4*)vb8;
      v2.u = *(const uint4*)(vb8 + 16);
    }
    O = __builtin_amdgcn_mfma_f32_32x32x16_bf16(v1.s, b1.s, O, 0, 0, 0);
    O = __builtin_amdgcn_mfma_f32_32x32x16_bf16(v2.s, b2.s, O, 0, 0, 0);
  }

  ls += __shfl_xor(ls, 32, 64);

  __shared__ float pm[4][64], pl[4][64];
  __shared__ float po[4][64][4];
  if (kh == 0) {
    pm[grp][l] = m;
    pl[grp][l] = ls;
    *(float4*)(&po[grp][l][0]) = make_float4(O[0], O[1], O[2], O[3]);
  }
  __syncthreads();
  if (kh == 1) {
    float mA = pm[grp][l], lsA = pl[grp][l];
    float nm = fmaxf(m, mA);
    float wB = __expf(m - nm), wA = __expf(mA - nm);
    float4 oA = *(const float4*)(&po[grp][l][0]);
    float inv = 1.0f / (ls * wB + lsA * wA);
    int bq2 = q >> 7, sq = ((q & 127) << 3) | slo;
    float* op = ao + (((size_t)((bq2 << 10) | sq)) << 6) + (h << 3) + (g << 2);
    *(float4*)op = make_float4((O[0] * wB + oA.x * wA) * inv,
                               (O[1] * wB + oA.y * wA) * inv,
                               (O[2] * wB + oA.z * wA) * inv,
                               (O[3] * wB + oA.w * wA) * inv);
  }
}

// K4 v4: fused residual+LN+FFN+LN (+ optional qkv emission for NEXT layer).
// 4 rows/wave, 16 rows/block, W2 in LDS bf16 (round-14). After LN2, x_out
// rows staged into the dead aos buffer; barrier; threads 0-191 each compute
// one qkv column for all 16 rows (weights amortized 16x) and emit qb/kb/vt.
template <bool EMIT>
__global__ __launch_bounds__(256, 2) void k_fused(
    const float* x_in, const float* __restrict__ ao,
    const float* __restrict__ Wo, const float* __restrict__ bo,
    const float* __restrict__ g1, const float* __restrict__ be1,
    const float* __restrict__ W1, const float* __restrict__ b1,
    const float* __restrict__ W2, const float* __restrict__ b2,
    const float* __restrict__ g2, const float* __restrict__ be2,
    const float* __restrict__ Wq, const float* __restrict__ bq,
    const float* __restrict__ gran, const int* __restrict__ tidx,
    unsigned int* __restrict__ qbo, unsigned int* __restrict__ kbo,
    unsigned short* __restrict__ vto, float* __restrict__ x_out) {
  int t = threadIdx.x, w = t >> 6, c = t & 63;
  int ws = w << 2;
  int row_base = blockIdx.x << 4;
  int row0 = row_base + ws;
  __shared__ unsigned int w2b[8192];  // W2 bf16 pairs, 32KB
  __shared__ float aos[16][64];       // ao staging, then x_out staging
  __shared__ float x1s[16][64];
  __shared__ float h1s[16][256];
  for (int i = t; i < 8192; i += 256) {
    float2 f = *(const float2*)(W2 + 2 * i);
    w2b[i] = bf16rne(f.x) | (bf16rne(f.y) << 16);
  }
  float xin[4];
#pragma unroll
  for (int r = 0; r < 4; ++r) {
    aos[ws + r][c] = ao[(size_t)(row0 + r) * 64 + c];
    xin[r] = x_in[(size_t)(row0 + r) * 64 + c];
  }
  // ---- proj + residual + LN1 (wave-private, no barrier)
  float acc[4];
  float bov = bo[c];
#pragma unroll
  for (int r = 0; r < 4; ++r) acc[r] = bov;
#pragma unroll 4
  for (int k4 = 0; k4 < 16; ++k4) {
    float w0 = Wo[(4 * k4 + 0) * 64 + c], w1 = Wo[(4 * k4 + 1) * 64 + c];
    float w2 = Wo[(4 * k4 + 2) * 64 + c], w3 = Wo[(4 * k4 + 3) * 64 + c];
#pragma unroll
    for (int r = 0; r < 4; ++r) {
      float4 av = *(const float4*)(&aos[ws + r][4 * k4]);
      acc[r] = fmaf(av.x, w0, acc[r]);
      acc[r] = fmaf(av.y, w1, acc[r]);
      acc[r] = fmaf(av.z, w2, acc[r]);
      acc[r] = fmaf(av.w, w3, acc[r]);
    }
  }
  float g1v = g1[c], be1v = be1[c];
  float x1v[4];
#pragma unroll
  for (int r = 0; r < 4; ++r) {
    float y = acc[r] + xin[r];
    float s1 = wave_sum64(y), s2 = wave_sum64(y * y);
    float mean = s1 * 0.015625f, var = s2 * 0.015625f - mean * mean;
    x1v[r] = (y - mean) * rsqrtf(var + EPS) * g1v + be1v;
    x1s[ws + r][c] = x1v[r];
  }
  // ---- ffn1
  float4 h[4];
  float4 b1v = *(const float4*)(b1 + 4 * c);
#pragma unroll
  for (int r = 0; r < 4; ++r) h[r] = b1v;
#pragma unroll 4
  for (int k4 = 0; k4 < 16; ++k4) {
    float4 w0 = *(const float4*)(W1 + (size_t)(4 * k4 + 0) * 256 + 4 * c);
    float4 w1 = *(const float4*)(W1 + (size_t)(4 * k4 + 1) * 256 + 4 * c);
    float4 w2 = *(const float4*)(W1 + (size_t)(4 * k4 + 2) * 256 + 4 * c);
    float4 w3 = *(const float4*)(W1 + (size_t)(4 * k4 + 3) * 256 + 4 * c);
#pragma unroll
    for (int r = 0; r < 4; ++r) {
      float4 xv = *(const float4*)(&x1s[ws + r][4 * k4]);
      h[r].x = fmaf(xv.x, w0.x, h[r].x); h[r].y = fmaf(xv.x, w0.y, h[r].y);
      h[r].z = fmaf(xv.x, w0.z, h[r].z); h[r].w = fmaf(xv.x, w0.w, h[r].w);
      h[r].x = fmaf(xv.y, w1.x, h[r].x); h[r].y = fmaf(xv.y, w1.y, h[r].y);
      h[r].z = fmaf(xv.y, w1.z, h[r].z); h[r].w = fmaf(xv.y, w1.w, h[r].w);
      h[r].x = fmaf(xv.z, w2.x, h[r].x); h[r].y = fmaf(xv.z, w2.y, h[r].y);
      h[r].z = fmaf(xv.z, w2.z, h[r].z); h[r].w = fmaf(xv.z, w2.w, h[r].w);
      h[r].x = fmaf(xv.w, w3.x, h[r].x); h[r].y = fmaf(xv.w, w3.y, h[r].y);
      h[r].z = fmaf(xv.w, w3.z, h[r].z); h[r].w = fmaf(xv.w, w3.w, h[r].w);
    }
  }
#pragma unroll
  for (int r = 0; r < 4; ++r) {
    h[r].x = fmaxf(h[r].x, 0.f); h[r].y = fmaxf(h[r].y, 0.f);
    h[r].z = fmaxf(h[r].z, 0.f); h[r].w = fmaxf(h[r].w, 0.f);
    *(float4*)(&h1s[ws + r][4 * c]) = h[r];
  }
  __syncthreads();  // W2 staging complete
  // ---- ffn2 from LDS bf16 + LN2
  int sh = (c & 1) ? 0 : 16;
  int wb2 = c >> 1;
  float acc2[4];
  float b2v = b2[c];
#pragma unroll
  for (int r = 0; r < 4; ++r) acc2[r] = b2v;
#pragma unroll 4
  for (int k4 = 0; k4 < 64; ++k4) {
    float w0 = __uint_as_float((w2b[(4 * k4 + 0) * 32 + wb2] << sh) & 0xffff0000u);
    float w1 = __uint_as_float((w2b[(4 * k4 + 1) * 32 + wb2] << sh) & 0xffff0000u);
    float w2 = __uint_as_float((w2b[(4 * k4 + 2) * 32 + wb2] << sh) & 0xffff0000u);
    float w3 = __uint_as_float((w2b[(4 * k4 + 3) * 32 + wb2] << sh) & 0xffff0000u);
#pragma unroll
    for (int r = 0; r < 4; ++r) {
      float4 hv = *(const float4*)(&h1s[ws + r][4 * k4]);
      acc2[r] = fmaf(hv.x, w0, acc2[r]);
      acc2[r] = fmaf(hv.y, w1, acc2[r]);
      acc2[r] = fmaf(hv.z, w2, acc2[r]);
      acc2[r] = fmaf(hv.w, w3, acc2[r]);
    }
  }
  float g2v = g2[c], be2v = be2[c];
#pragma unroll
  for (int r = 0; r < 4; ++r) {
    float y2 = acc2[r] + x1v[r];
    float t1 = wave_sum64(y2), t2 = wave_sum64(y2 * y2);
    float mean2 = t1 * 0.015625f, var2 = t2 * 0.015625f - mean2 * mean2;
    float xo = (y2 - mean2) * rsqrtf(var2 + EPS) * g2v + be2v;
    x_out[(size_t)(row0 + r) * 64 + c] = xo;
    aos[ws + r][c] = xo;  // stage for qkv phase (aos is dead after proj)
  }
  if (EMIT) {
    __syncthreads();  // x_out rows visible block-wide
    if (t < 192) {
      float qa[16];
      float bias = bq[t];
#pragma unroll
      for (int r = 0; r < 16; ++r) qa[r] = bias;
      for (int k = 0; k < 64; ++k) {
        float wqv = Wq[k * 192 + t];
#pragma unroll
        for (int r = 0; r < 16; ++r) qa[r] = fmaf(aos[r][k], wqv, qa[r]);
      }
      int cq = t & 63, hh = cq >> 3, hd = t & 7;
      int bb = row_base >> 10;
      const float scl = 0.35355339059327373f;
#pragma unroll
      for (int r = 0; r < 16; ++r) {
        float o = qa[r];
        if (t < 128) o += gran[tidx[2 * (r & 7) + 1] * 64 + cq];
        int row = row_base + r;
        int s2 = (bb << 7) | ((row & 1023) >> 3);
        int bh = ((r & 7) << 3) | hh;
        size_t base = ((size_t)(bh << 10)) | s2;
        if (t < 64) {
          o *= scl;
          float nb = __shfl_down(o, 1, 64);
          if ((hd & 1) == 0)
            qbo[(base << 2) + (hd >> 1)] = bf16rne(o) | (bf16rne(nb) << 16);
        } else if (t < 128) {
          float nb = __shfl_down(o, 1, 64);
          if ((hd & 1) == 0)
            kbo[(base << 2) + (hd >> 1)] = bf16rne(o) | (bf16rne(nb) << 16);
        } else {
          vto[((size_t)bh << 13) + (hd << 10) + s2] = (unsigned short)bf16rne(o);
        }
      }
    }
  }
}

// K6: out = x @ W_fc + b_fc
__global__ __launch_bounds__(256) void k_head(
    const float* __restrict__ x, const float* __restrict__ Wfc,
    const float* __restrict__ bfc, float* __restrict__ out) {
  int gid = blockIdx.x * 256 + threadIdx.x;
  int r = gid >> 5, o = gid & 31;
  if (o >= 31) return;
  float acc = bfc[o];
  const float* xr = x + (size_t)r * 64;
#pragma unroll
  for (int i = 0; i < 64; ++i) acc = fmaf(xr[i], Wfc[i * 31 + o], acc);
  out[(size_t)r * 31 + o] = acc;
}

extern "C" void kernel_launch(void* const* d_in, const int* in_sizes, int n_in,
                              void* d_out, int out_size, void* d_ws, size_t ws_size,
                              hipStream_t stream) {
  const float* weather = (const float*)d_in[0];
  const float* coords  = (const float*)d_in[1];
  const int*   tidx    = (const int*)d_in[2];
  const float* W_emb   = (const float*)d_in[3];
  const float* b_emb   = (const float*)d_in[4];
  const float* W_qkv   = (const float*)d_in[5];
  const float* b_qkv   = (const float*)d_in[6];
  const float* W_out   = (const float*)d_in[7];
  const float* b_out   = (const float*)d_in[8];
  const float* gran    = (const float*)d_in[9];
  const float* g1      = (const float*)d_in[10];
  const float* be1     = (const float*)d_in[11];
  const float* W1      = (const float*)d_in[12];
  const float* b1      = (const float*)d_in[13];
  const float* W2      = (const float*)d_in[14];
  const float* b2      = (const float*)d_in[15];
  const float* g2      = (const float*)d_in[16];
  const float* be2     = (const float*)d_in[17];
  const float* W_fc    = (const float*)d_in[18];
  const float* b_fc    = (const float*)d_in[19];
  float* out = (float*)d_out;

  // workspace: x(2MB) | qb(1MB) | kb(1MB) | vt(1MB) | ao(2MB) = 7MB
  float* x = (float*)d_ws;
  unsigned int* qbw = (unsigned int*)(x + 8192 * 64);
  unsigned int* kbw = qbw + 64 * 1024 * 4;
  unsigned short* vtw = (unsigned short*)(kbw + 64 * 1024 * 4);
  float* ao = (float*)(vtw + 64 * 8 * 1024);

  k_qkv0<<<1024, 192, 0, stream>>>(weather, coords, W_emb, b_emb,
                                   W_qkv, b_qkv, gran, tidx,
                                   x, qbw, kbw, vtw);
  for (int l = 0; l < 3; ++l) {
    k_attn<<<512, 512, 0, stream>>>(qbw, kbw, vtw, ao);
    if (l < 2) {
      k_fused<true><<<512, 256, 0, stream>>>(
          x, ao, W_out + l * 64 * 64, b_out + l * 64,
          g1 + l * 64, be1 + l * 64, W1 + l * 64 * 256, b1 + l * 256,
          W2 + l * 256 * 64, b2 + l * 64, g2 + l * 64, be2 + l * 64,
          W_qkv + (l + 1) * 64 * 192, b_qkv + (l + 1) * 192,
          gran + (l + 1) * 31 * 64, tidx, qbw, kbw, vtw, x);
    } else {
      k_fused<false><<<512, 256, 0, stream>>>(
          x, ao, W_out + l * 64 * 64, b_out + l * 64,
          g1 + l * 64, be1 + l * 64, W1 + l * 64 * 256, b1 + l * 256,
          W2 + l * 256 * 64, b2 + l * 64, g2 + l * 64, be2 + l * 64,
          nullptr, nullptr, nullptr, nullptr, nullptr, nullptr, nullptr, x);
    }
  }
  k_head<<<1024, 256, 0, stream>>>(x, W_fc, b_fc, out);
}